// Round 11
// baseline (243.718 us; speedup 1.0000x reference)
//
#include <hip/hip_runtime.h>
#include <hip/hip_bf16.h>

typedef __attribute__((ext_vector_type(8))) short bf16x8;   // 8 bf16 = 4 VGPR (MFMA A/B frag)
typedef __attribute__((ext_vector_type(4))) float f32x4;    // MFMA C/D frag

#define DEVI __device__ __forceinline__
#define AS1 __attribute__((address_space(1)))
#define AS3 __attribute__((address_space(3)))

constexpr int SEQ_   = 2048;
constexpr int HEADS  = 16;
constexpr int DHEAD  = 64;
constexpr int DMODEL = 1024;

DEVI unsigned short f2bf(float x) {
  __hip_bfloat16 h = __float2bfloat16(x);   // RNE
  return __builtin_bit_cast(unsigned short, h);
}

DEVI f32x4 MFMA(bf16x8 a, bf16x8 b, f32x4 c) {
  return __builtin_amdgcn_mfma_f32_16x16x32_bf16(a, b, c, 0, 0, 0);
}

DEVI unsigned int cvtpk(float lo, float hi) {   // dst.lo16=bf16(lo), dst.hi16=bf16(hi)
  unsigned int u;
  asm("v_cvt_pk_bf16_f32 %0, %1, %2" : "=v"(u) : "v"(lo), "v"(hi));
  return u;
}

// ---------------------------------------------------------------- convert ---
__global__ void conv3_kernel(const float* s0, const float* s1, const float* s2,
                             unsigned short* d0, unsigned short* d1, unsigned short* d2,
                             int n) {
  const float* s = (blockIdx.y == 0) ? s0 : (blockIdx.y == 1) ? s1 : s2;
  unsigned short* d = (blockIdx.y == 0) ? d0 : (blockIdx.y == 1) ? d1 : d2;
  int i = (blockIdx.x * 256 + threadIdx.x) * 8;
  if (i >= n) return;
  const float4* p = (const float4*)(s + i);
  float4 v0 = p[0], v1 = p[1];
  union { unsigned short u[8]; bf16x8 v; } t;
  t.u[0] = f2bf(v0.x); t.u[1] = f2bf(v0.y); t.u[2] = f2bf(v0.z); t.u[3] = f2bf(v0.w);
  t.u[4] = f2bf(v1.x); t.u[5] = f2bf(v1.y); t.u[6] = f2bf(v1.z); t.u[7] = f2bf(v1.w);
  *(bf16x8*)(d + i) = t.v;
}

__global__ void conv4_kernel(const float* s0, const float* s1, const float* s2,
                             const float* s3,
                             unsigned short* d0, unsigned short* d1,
                             unsigned short* d2, unsigned short* d3,
                             int n_w, int n_e) {
  const int y = blockIdx.y;
  const float* s = (y == 0) ? s0 : (y == 1) ? s1 : (y == 2) ? s2 : s3;
  unsigned short* d = (y == 0) ? d0 : (y == 1) ? d1 : (y == 2) ? d2 : d3;
  const int n = (y == 3) ? n_e : n_w;
  int i = (blockIdx.x * 256 + threadIdx.x) * 8;
  if (i >= n) return;
  const float4* p = (const float4*)(s + i);
  float4 v0 = p[0], v1 = p[1];
  union { unsigned short u[8]; bf16x8 v; } t;
  t.u[0] = f2bf(v0.x); t.u[1] = f2bf(v0.y); t.u[2] = f2bf(v0.z); t.u[3] = f2bf(v0.w);
  t.u[4] = f2bf(v1.x); t.u[5] = f2bf(v1.y); t.u[6] = f2bf(v1.z); t.u[7] = f2bf(v1.w);
  *(bf16x8*)(d + i) = t.v;
}

// ------------------------------------------------------------- projection ---
// z==0 (Q): out (b,h,s,d), pre-scaled by 0.125*log2(e) (exp2 softmax fold).
// z==1 (K): 4KB tiles (per 32 t) in MFMA fragment order.
// z==2 (V): 4KB tiles (per 32 t) frag order with t' = 2*(t&15) + (t>>4)
//           (matches attn's b32 P-write order).
__global__ __launch_bounds__(256) void proj3_kernel(
    const unsigned short* __restrict__ X0, const unsigned short* __restrict__ X1,
    const unsigned short* __restrict__ X2,
    const unsigned short* __restrict__ W0, const unsigned short* __restrict__ W1,
    const unsigned short* __restrict__ W2,
    const float* __restrict__ bi0, const float* __restrict__ bi1,
    const float* __restrict__ bi2,
    unsigned short* __restrict__ o0, unsigned short* __restrict__ o1,
    unsigned short* __restrict__ o2) {
  const int z = blockIdx.z;
  const unsigned short* X = (z == 0) ? X0 : (z == 1) ? X1 : X2;
  const unsigned short* W = (z == 0) ? W0 : (z == 1) ? W1 : W2;
  const float* bias        = (z == 0) ? bi0 : (z == 1) ? bi1 : bi2;
  unsigned short* out      = (z == 0) ? o0 : (z == 1) ? o1 : o2;

  __shared__ unsigned short Abuf[2][128 * 32];
  __shared__ unsigned short Bbuf[2][128 * 32];
  const int tid  = threadIdx.x;
  const int lane = tid & 63, wv = tid >> 6;
  const int q = lane >> 4, r = lane & 15;
  const int wrow = wv >> 1, wcol = wv & 1;
  const int rowA0 = blockIdx.x * 128, colB0 = blockIdx.y * 128;

  const char* Ag = (const char*)(X + (size_t)rowA0 * DMODEL);
  const char* Bg = (const char*)(W + (size_t)colB0 * DMODEL);

  f32x4 acc[4][4] = {};

  auto stage = [&](int ks, int buf) {
    const int koff = ks * 64;
#pragma unroll
    for (int i = 0; i < 2; ++i) {
      const int b   = (i * 256 + tid) * 16;
      const int row = b >> 6, col = b & 63;
      __builtin_amdgcn_global_load_lds(
          (const AS1 void*)(Ag + (size_t)row * (DMODEL * 2) + koff + col),
          (AS3 void*)((char*)&Abuf[buf][0] + i * 4096 + wv * 1024),
          16, 0, 0);
      __builtin_amdgcn_global_load_lds(
          (const AS1 void*)(Bg + (size_t)row * (DMODEL * 2) + koff + col),
          (AS3 void*)((char*)&Bbuf[buf][0] + i * 4096 + wv * 1024),
          16, 0, 0);
    }
  };

  stage(0, 0);
  for (int ks = 0; ks < 32; ++ks) {
    __syncthreads();
    if (ks + 1 < 32) stage(ks + 1, (ks + 1) & 1);
    const unsigned short* A  = &Abuf[ks & 1][0];
    const unsigned short* Bt = &Bbuf[ks & 1][0];
    bf16x8 af[4], bfr[4];
#pragma unroll
    for (int t = 0; t < 4; ++t) {
      af[t]  = *(const bf16x8*)(A  + (wrow * 64 + t * 16 + r) * 32 + q * 8);
      bfr[t] = *(const bf16x8*)(Bt + (wcol * 64 + t * 16 + r) * 32 + q * 8);
    }
#pragma unroll
    for (int m = 0; m < 4; ++m)
#pragma unroll
      for (int n = 0; n < 4; ++n)
        acc[m][n] = MFMA(af[m], bfr[n], acc[m][n]);
  }

#pragma unroll
  for (int m = 0; m < 4; ++m) {
#pragma unroll
    for (int n = 0; n < 4; ++n) {
      const int e  = colB0 + wcol * 64 + n * 16 + r;
      const float bv = bias[e];
      const int h = e >> 6, dd = e & 63;
      const int nrow0 = rowA0 + wrow * 64 + m * 16 + q * 4;
      const int bb = nrow0 >> 11, ss0 = nrow0 & 2047;
      const size_t bh = (size_t)(bb * HEADS + h);
      if (z == 0) {
#pragma unroll
        for (int j = 0; j < 4; ++j)
          out[(bh * SEQ_ + (ss0 + j)) * DHEAD + dd] =
              f2bf((acc[m][n][j] + bv) * 0.1803368801111244f);   // 0.125*log2e
      } else if (z == 1) {
#pragma unroll
        for (int j = 0; j < 4; ++j) {
          const int s = ss0 + j;
          const size_t off = (bh * 64 + (size_t)(s >> 5)) * 2048
                           + (size_t)(((dd >> 5) * 2 + ((s >> 4) & 1)) * 512)
                           + (size_t)(((((dd & 31) >> 3) << 4) + (s & 15)) * 8)
                           + (dd & 7);
          out[off] = f2bf(acc[m][n][j] + bv);
        }
      } else {
        // V: 4KB tile per 32 t, t' = 2*(t&15) + (t>>4)
#pragma unroll
        for (int j = 0; j < 4; ++j) {
          const int s = ss0 + j;
          const int t = s & 31;
          const int tp = 2 * (t & 15) + (t >> 4);
          const size_t off = (bh * 64 + (size_t)(s >> 5)) * 2048
                           + (size_t)((dd >> 4) * 512)
                           + (size_t)(((((tp >> 3) << 4) | (dd & 15))) * 8)
                           + (tp & 7);
          out[off] = f2bf(acc[m][n][j] + bv);
        }
      }
    }
  }
}

// -------------------------------------------------------------- attention ---
// 1024 blocks x 256 thr (4 waves x 32 rows = 128-row tile), 4 blocks/CU
// (LDS 34KB, VGPR<=128 via launch_bounds(256,4)). KVBLK=32, ring-3 LDS,
// counted s_waitcnt vmcnt(6) + raw s_barrier (2 stage + 4 Er ops/wave/iter).
// Perfect balance: tile pair (15-p, p) iters (64-4p, 4p+4) both /4 -> block
// (p,qq) runs quarter qq of EACH tile = 17 iters, all blocks equal, no empty
// strips. 4 bf16 partial slots per tile; reduce merges. exp2 softmax (log2e
// folded into Q). P via 1 cvt_pk b32 write/(rt,j); V t'-permuted; PV = 1
// MFMA/(rt,dc); skew gather = 2 shuffles/(rt,j).
struct ErSet { bf16x8 e[4]; };                  // 2 fresh tiles x 2 kc

__global__ __launch_bounds__(256, 4) void attn_kernel(
    const unsigned short* __restrict__ qb, const unsigned short* __restrict__ kt,
    const unsigned short* __restrict__ vt, const unsigned short* __restrict__ Er,
    unsigned short* __restrict__ pO, float* __restrict__ pL) {
  __shared__ unsigned short k_lds[3][2048];     // 4KB/buf frag-order K tile
  __shared__ unsigned short v_lds[3][2048];     // 4KB/buf t'-permuted V tile
  __shared__ unsigned short p_lds[4][32][40];   // [s][t'] b32-written P (80B rows)

  const int tid  = threadIdx.x;
  const int lane = tid & 63, wv = tid >> 6;     // 4 waves
  const int q = lane >> 4, r = lane & 15;

  const int lid = blockIdx.x;
  const int xcd = lid & 7, idx = lid >> 3;      // 128 per XCD
  const int bh  = (xcd << 2) | (idx & 3);       // 4 bh pinned per XCD L2
  const int rest = idx >> 2;                    // 0..31
  const int p = rest >> 2, qq = rest & 3;       // pair p (0..7), quarter qq

  const unsigned short* qbh = qb + (size_t)bh * SEQ_ * DHEAD;
  const char* ktb = (const char*)(kt + (size_t)bh * 64 * 2048);
  const char* vtb = (const char*)(vt + (size_t)bh * 64 * 2048);
  const f32x4 zero4 = {0.f, 0.f, 0.f, 0.f};

  // staging roles: waves 0,1 -> K; waves 2,3 -> V; 2KB (2 x 1KB DMA) each
  const char* sgbase = (wv < 2) ? ktb : vtb;
  char* sdst0 = (char*)((wv < 2) ? &k_lds[0][0] : &v_lds[0][0]);
  const int shalf = (wv & 1) * 2048;
  const int soff  = lane * 16;

  auto stage = [&](int it, int buf) {           // 2 vmem ops / wave
    const char* src = sgbase + (size_t)it * 4096 + shalf + soff;
    char* dst = sdst0 + buf * 4096 + shalf;
    __builtin_amdgcn_global_load_lds((const AS1 void*)(src),
                                     (AS3 void*)(dst), 16, 0, 0);
    __builtin_amdgcn_global_load_lds((const AS1 void*)(src + 1024),
                                     (AS3 void*)(dst + 1024), 16, 0, 0);
  };

  auto run_strip = [&](int T, int it0, int it1, unsigned short* po, float* pl) {
    const int s0 = T * 128 + wv * 32;
    __syncthreads();                            // prev strip done with bufs
    stage(it0, 0);

    bf16x8 qf[2][2];
#pragma unroll
    for (int rt = 0; rt < 2; ++rt) {
      qf[rt][0] = *(const bf16x8*)(qbh + (size_t)(s0 + rt * 16 + r) * DHEAD + q * 8);
      qf[rt][1] = *(const bf16x8*)(qbh + (size_t)(s0 + rt * 16 + r) * DHEAD + 32 + q * 8);
    }

    // lattice qer[rt][m]: QEr[s0+rt*16+q*4+j][B0(it)+16m+r], window m=0..3
    f32x4 qer[2][4];
    {
      const int B0 = 2016 + 32 * it0 - s0;
#pragma unroll
      for (int m = 0; m < 2; ++m) {
        int l = B0 + m * 16 + r; l = l < 2047 ? l : 2047;
        bf16x8 e0 = *(const bf16x8*)(Er + (size_t)l * DHEAD + q * 8);
        bf16x8 e1 = *(const bf16x8*)(Er + (size_t)l * DHEAD + 32 + q * 8);
#pragma unroll
        for (int rt = 0; rt < 2; ++rt)
          qer[rt][m] = MFMA(qf[rt][1], e1, MFMA(qf[rt][0], e0, zero4));
      }
    }

    auto loadE = [&](ErSet& es, int it) {       // 4 vmem ops / wave
      const int B0 = 2016 + 32 * it - s0;
#pragma unroll
      for (int mi = 0; mi < 2; ++mi) {
        int l = B0 + 32 + mi * 16 + r;
        l = l < 2047 ? l : 2047;                // clamped rows feed masked cols
        es.e[mi * 2 + 0] = *(const bf16x8*)(Er + (size_t)l * DHEAD + q * 8);
        es.e[mi * 2 + 1] = *(const bf16x8*)(Er + (size_t)l * DHEAD + 32 + q * 8);
      }
    };

    f32x4 oacc[2][4] = {};
    float lpart[2][4] = {};

    auto body = [&](int it, int cur, const ErSet& es) {
      const int t0 = it * 32;
      if (t0 > s0 + 31) return;                 // masked tail (wave-uniform)
      const unsigned short* KL = &k_lds[cur][0];
      const unsigned short* VL = &v_lds[cur][0];

      bf16x8 kf[2][2];
#pragma unroll
      for (int ct = 0; ct < 2; ++ct)
#pragma unroll
        for (int kc = 0; kc < 2; ++kc)
          kf[ct][kc] = *(const bf16x8*)(KL + (kc * 2 + ct) * 512 + lane * 8);

      f32x4 s4[2][2];
      __builtin_amdgcn_s_setprio(1);
#pragma unroll
      for (int rt = 0; rt < 2; ++rt)
#pragma unroll
        for (int ct = 0; ct < 2; ++ct)
          s4[rt][ct] = MFMA(qf[rt][1], kf[ct][1], MFMA(qf[rt][0], kf[ct][0], zero4));
#pragma unroll
      for (int rt = 0; rt < 2; ++rt)
#pragma unroll
        for (int mi = 0; mi < 2; ++mi)
          qer[rt][2 + mi] = MFMA(qf[rt][1], es.e[mi * 2 + 1],
                                 MFMA(qf[rt][0], es.e[mi * 2 + 0], zero4));
      __builtin_amdgcn_s_setprio(0);

      const int d0 = t0 - s0;
#pragma unroll
      for (int rt = 0; rt < 2; ++rt) {
        const int a = 1 - rt;                   // window base tile
#pragma unroll
        for (int j = 0; j < 4; ++j) {
          const unsigned int pk = cvtpk(qer[rt][a][j], qer[rt][a + 1][j]);
          const float f2 = qer[rt][a + 2][j];
          const int srcl = (q << 4) | ((15 + r - q * 4 - j) & 15);
          const unsigned int A = (unsigned int)__shfl((int)pk, srcl);
          const float g2 = __shfl(f2, srcl);
          const float g0 = __builtin_bit_cast(float, A << 16);
          const float g1 = __builtin_bit_cast(float, A & 0xffff0000u);
          const bool hi = (r > q * 4 + j);
          const float b0 = hi ? g1 : g0;
          const float b1 = hi ? g2 : g1;
          const int A_ = rt * 16 + q * 4 + j - r - d0;   // keep iff ct*16 <= A_
          const float p0 = (A_ >= 0)  ? exp2f(s4[rt][0][j] + b0) : 0.f;
          const float p1 = (A_ >= 16) ? exp2f(s4[rt][1][j] + b1) : 0.f;
          lpart[rt][j] += p0 + p1;
          const int sl = rt * 16 + q * 4 + j;
          *(unsigned int*)&p_lds[wv][sl][2 * r] = cvtpk(p0, p1);   // t' = 2r+ct
        }
      }

      bf16x8 vf[4];
#pragma unroll
      for (int dc = 0; dc < 4; ++dc)
        vf[dc] = *(const bf16x8*)(VL + dc * 512 + lane * 8);
      __builtin_amdgcn_s_setprio(1);
#pragma unroll
      for (int rt = 0; rt < 2; ++rt) {
        bf16x8 pf = *(const bf16x8*)(&p_lds[wv][rt * 16 + r][0] + q * 8);
#pragma unroll
        for (int dc = 0; dc < 4; ++dc)
          oacc[rt][dc] = MFMA(pf, vf[dc], oacc[rt][dc]);
      }
      __builtin_amdgcn_s_setprio(0);

#pragma unroll
      for (int rt = 0; rt < 2; ++rt) { qer[rt][0] = qer[rt][2]; qer[rt][1] = qer[rt][3]; }
    };

    ErSet eA, eB;
    loadE(eA, it0);

    int it = it0, cur = 0;
    while (true) {
      int nx = cur + 1; if (nx == 3) nx = 0;
      int itn = (it + 1 < it1) ? it + 1 : it1 - 1;
      stage(itn, nx);
      loadE(eB, itn);
      asm volatile("s_waitcnt vmcnt(6)\n\ts_barrier" ::: "memory");
      body(it, cur, eA);
      cur = nx;
      if (++it >= it1) break;
      nx = cur + 1; if (nx == 3) nx = 0;
      itn = (it + 1 < it1) ? it + 1 : it1 - 1;
      stage(itn, nx);
      loadE(eA, itn);
      asm volatile("s_waitcnt vmcnt(6)\n\ts_barrier" ::: "memory");
      body(it, cur, eB);
      cur = nx;
      if (++it >= it1) break;
    }

    // epilogue: bf16 partial O + f32 partial l (unnormalized)
#pragma unroll
    for (int rt = 0; rt < 2; ++rt)
#pragma unroll
      for (int j = 0; j < 4; ++j) {
        float ls = lpart[rt][j];
#pragma unroll
        for (int d = 1; d < 16; d <<= 1) ls += __shfl_xor(ls, d);
        const int row = wv * 32 + rt * 16 + q * 4 + j;
#pragma unroll
        for (int dc = 0; dc < 4; ++dc)
          po[(size_t)row * 64 + dc * 16 + r] = f2bf(oacc[rt][dc][j]);
        if (r == 0) pl[row] = ls;
      }
  };

  const int TA = 15 - p, lenA = 16 - p;         // big tile: 64-4p iters = 4*lenA
  const int TB = p,      lenB = p + 1;          // small tile: 4p+4 iters = 4*lenB
  const size_t slotA = ((size_t)bh * 16 + TA) * 4 + qq;
  const size_t slotB = ((size_t)bh * 16 + TB) * 4 + qq;

  run_strip(TA, qq * lenA, (qq + 1) * lenA, pO + slotA * 8192, pL + slotA * 128);
  run_strip(TB, qq * lenB, (qq + 1) * lenB, pO + slotB * 8192, pL + slotB * 128);
}

// ---------------------------------------------------------------- reduce ----
// out = sum(4 bf16 partial O) / sum(4 partial l) per 128-row tile.
__global__ __launch_bounds__(256) void reduce_kernel(const unsigned short* __restrict__ pO,
                                                     const float* __restrict__ pL,
                                                     float* __restrict__ out) {
  const int slot = blockIdx.x;                  // bh*16 + T
  const int bh = slot >> 4, T = slot & 15;
  const int bb = bh >> 4, hh = bh & 15;
  const int tid = threadIdx.x;
  const int row = tid >> 1, half = (tid & 1) * 32;

  float l = 0.f;
#pragma unroll
  for (int k = 0; k < 4; ++k) l += pL[((size_t)slot * 4 + k) * 128 + row];
  const float inv = 1.0f / l;

  float acc[32] = {};
#pragma unroll
  for (int k = 0; k < 4; ++k) {
    const unsigned short* src = pO + ((size_t)slot * 4 + k) * 8192 + row * 64 + half;
#pragma unroll
    for (int c = 0; c < 4; ++c) {
      union { bf16x8 v; unsigned short u[8]; } w;
      w.v = *(const bf16x8*)(src + c * 8);
#pragma unroll
      for (int e = 0; e < 8; ++e)
        acc[c * 8 + e] += __builtin_bit_cast(float, (unsigned int)w.u[e] << 16);
    }
  }

  float* dst = out + ((size_t)(bb * SEQ_) + T * 128 + row) * DMODEL + hh * DHEAD + half;
#pragma unroll
  for (int c = 0; c < 8; ++c) {
    float4 o;
    o.x = acc[c * 4 + 0] * inv; o.y = acc[c * 4 + 1] * inv;
    o.z = acc[c * 4 + 2] * inv; o.w = acc[c * 4 + 3] * inv;
    ((float4*)dst)[c] = o;
  }
}

// ------------------------------------------------------------------ launch ---
extern "C" void kernel_launch(void* const* d_in, const int* in_sizes, int n_in,
                              void* d_out, int out_size, void* d_ws, size_t ws_size,
                              hipStream_t stream) {
  const float* query = (const float*)d_in[0];
  const float* key   = (const float*)d_in[1];
  const float* value = (const float*)d_in[2];
  const float* Wq    = (const float*)d_in[3];
  const float* bq    = (const float*)d_in[4];
  const float* Wk    = (const float*)d_in[5];
  const float* bk    = (const float*)d_in[6];
  const float* Wv    = (const float*)d_in[7];
  const float* bv    = (const float*)d_in[8];
  const float* Er    = (const float*)d_in[9];

  char* ws = (char*)d_ws;
  unsigned short* qb   = (unsigned short*)(ws + (0u  << 20));  // 8MB
  unsigned short* ktil = (unsigned short*)(ws + (8u  << 20));  // 8MB
  unsigned short* vtil = (unsigned short*)(ws + (16u << 20));  // 8MB
  unsigned short* pO   = (unsigned short*)(ws + (24u << 20));  // 32MB bf16 [24,56)
  float*          pL   = (float*)(ws + (56u << 20));           // 1MB (Wqb dead post-proj)
  unsigned short* Xq   = (unsigned short*)(ws + (32u << 20));  // proj inputs (pre-attn only)
  unsigned short* Xk   = (unsigned short*)(ws + (40u << 20));
  unsigned short* Xv   = (unsigned short*)(ws + (48u << 20));
  unsigned short* Wqb  = (unsigned short*)(ws + (56u << 20));  // 2MB (clobbered by pL post-use)
  unsigned short* Wkb  = (unsigned short*)(ws + (58u << 20));
  unsigned short* Wvb  = (unsigned short*)(ws + (60u << 20));
  unsigned short* Erb  = (unsigned short*)(ws + (62u << 20));  // 256KB

  conv3_kernel<<<dim3(2048, 3), 256, 0, stream>>>(query, key, value, Xq, Xk, Xv,
                                                  2 * SEQ_ * DMODEL);
  conv4_kernel<<<dim3(512, 4), 256, 0, stream>>>(Wq, Wk, Wv, Er,
                                                 Wqb, Wkb, Wvb, Erb,
                                                 DMODEL * DMODEL, SEQ_ * DHEAD);

  proj3_kernel<<<dim3(32, 8, 3), 256, 0, stream>>>(Xq, Xk, Xv, Wqb, Wkb, Wvb,
                                                   bq, bk, bv, qb, ktil, vtil);

  attn_kernel<<<dim3(1024), 256, 0, stream>>>(qb, ktil, vtil, Erb, pO, pL);

  reduce_kernel<<<dim3(512), 256, 0, stream>>>(pO, pL, (float*)d_out);
}

// Round 12
// 160.795 us; speedup vs baseline: 1.5157x; 1.5157x over previous
//
#include <hip/hip_runtime.h>
#include <hip/hip_bf16.h>

typedef __attribute__((ext_vector_type(8))) short bf16x8;   // 8 bf16 = 4 VGPR (MFMA A/B frag)
typedef __attribute__((ext_vector_type(4))) float f32x4;    // MFMA C/D frag

#define DEVI __device__ __forceinline__
#define AS1 __attribute__((address_space(1)))
#define AS3 __attribute__((address_space(3)))

constexpr int SEQ_   = 2048;
constexpr int HEADS  = 16;
constexpr int DHEAD  = 64;
constexpr int DMODEL = 1024;

DEVI unsigned short f2bf(float x) {
  __hip_bfloat16 h = __float2bfloat16(x);   // RNE
  return __builtin_bit_cast(unsigned short, h);
}

DEVI f32x4 MFMA(bf16x8 a, bf16x8 b, f32x4 c) {
  return __builtin_amdgcn_mfma_f32_16x16x32_bf16(a, b, c, 0, 0, 0);
}

DEVI unsigned int cvtpk(float lo, float hi) {   // dst.lo16=bf16(lo), dst.hi16=bf16(hi)
  unsigned int u;
  asm("v_cvt_pk_bf16_f32 %0, %1, %2" : "=v"(u) : "v"(lo), "v"(hi));
  return u;
}

// ---------------------------------------------------------------- convert ---
// weights (y=0..2) + Er (y=3) — X conversions are fused into proj3.
__global__ void conv4_kernel(const float* s0, const float* s1, const float* s2,
                             const float* s3,
                             unsigned short* d0, unsigned short* d1,
                             unsigned short* d2, unsigned short* d3,
                             int n_w, int n_e) {
  const int y = blockIdx.y;
  const float* s = (y == 0) ? s0 : (y == 1) ? s1 : (y == 2) ? s2 : s3;
  unsigned short* d = (y == 0) ? d0 : (y == 1) ? d1 : (y == 2) ? d2 : d3;
  const int n = (y == 3) ? n_e : n_w;
  int i = (blockIdx.x * 256 + threadIdx.x) * 8;
  if (i >= n) return;
  const float4* p = (const float4*)(s + i);
  float4 v0 = p[0], v1 = p[1];
  union { unsigned short u[8]; bf16x8 v; } t;
  t.u[0] = f2bf(v0.x); t.u[1] = f2bf(v0.y); t.u[2] = f2bf(v0.z); t.u[3] = f2bf(v0.w);
  t.u[4] = f2bf(v1.x); t.u[5] = f2bf(v1.y); t.u[6] = f2bf(v1.z); t.u[7] = f2bf(v1.w);
  *(bf16x8*)(d + i) = t.v;
}

// ------------------------------------------------------------- projection ---
// A-side reads fp32 X DIRECTLY (conv fused): reg-stage 16 floats/thread,
// v_cvt_pk_bf16_f32, 2x ds_write_b128; aA/aB ping-pong so loads for ks+1
// overlap compute(ks). B-side (bf16 W) keeps global_load_lds.
// z==0 (Q): out (b,h,s,d), pre-scaled by 0.125.
// z==1 (K): 4KB tiles (per 32 t) in MFMA fragment order.
// z==2 (V): 8KB tiles (per 64 t) frag order with t' = 4*(t&15) + (t>>4).
__global__ __launch_bounds__(256) void proj3_kernel(
    const float* __restrict__ X0, const float* __restrict__ X1,
    const float* __restrict__ X2,
    const unsigned short* __restrict__ W0, const unsigned short* __restrict__ W1,
    const unsigned short* __restrict__ W2,
    const float* __restrict__ bi0, const float* __restrict__ bi1,
    const float* __restrict__ bi2,
    unsigned short* __restrict__ o0, unsigned short* __restrict__ o1,
    unsigned short* __restrict__ o2) {
  const int z = blockIdx.z;
  const float* X = (z == 0) ? X0 : (z == 1) ? X1 : X2;
  const unsigned short* W = (z == 0) ? W0 : (z == 1) ? W1 : W2;
  const float* bias        = (z == 0) ? bi0 : (z == 1) ? bi1 : bi2;
  unsigned short* out      = (z == 0) ? o0 : (z == 1) ? o1 : o2;

  __shared__ unsigned short Abuf[2][128 * 32];
  __shared__ unsigned short Bbuf[2][128 * 32];
  const int tid  = threadIdx.x;
  const int lane = tid & 63, wv = tid >> 6;
  const int q = lane >> 4, r = lane & 15;
  const int wrow = wv >> 1, wcol = wv & 1;
  const int rowA0 = blockIdx.x * 128, colB0 = blockIdx.y * 128;

  const float* Ag = X + (size_t)rowA0 * DMODEL;
  const char*  Bg = (const char*)(W + (size_t)colB0 * DMODEL);

  const int arow = tid >> 1, aseg = (tid & 1) * 16;
  const float* Arow = Ag + (size_t)arow * DMODEL + aseg;
  unsigned short* Adst = &Abuf[0][arow * 32 + aseg];

  float4 aA[4], aB[4];
  auto loadA = [&](float4* a4, int ks) {
    const float4* src = (const float4*)(Arow + ks * 32);
    a4[0] = src[0]; a4[1] = src[1]; a4[2] = src[2]; a4[3] = src[3];
  };
  auto writeA = [&](const float4* a4, int buf) {
    union { unsigned int u[4]; bf16x8 v; } p0, p1;
    p0.u[0] = cvtpk(a4[0].x, a4[0].y); p0.u[1] = cvtpk(a4[0].z, a4[0].w);
    p0.u[2] = cvtpk(a4[1].x, a4[1].y); p0.u[3] = cvtpk(a4[1].z, a4[1].w);
    p1.u[0] = cvtpk(a4[2].x, a4[2].y); p1.u[1] = cvtpk(a4[2].z, a4[2].w);
    p1.u[2] = cvtpk(a4[3].x, a4[3].y); p1.u[3] = cvtpk(a4[3].z, a4[3].w);
    *(bf16x8*)(Adst + buf * (128 * 32))     = p0.v;
    *(bf16x8*)(Adst + buf * (128 * 32) + 8) = p1.v;
  };
  auto stageB = [&](int ks, int buf) {
    const int koff = ks * 64;
#pragma unroll
    for (int i = 0; i < 2; ++i) {
      const int b   = (i * 256 + tid) * 16;
      const int row = b >> 6, col = b & 63;
      __builtin_amdgcn_global_load_lds(
          (const AS1 void*)(Bg + (size_t)row * (DMODEL * 2) + koff + col),
          (AS3 void*)((char*)&Bbuf[buf][0] + i * 4096 + wv * 1024),
          16, 0, 0);
    }
  };

  f32x4 acc[4][4] = {};

  auto compute = [&](int cur) {
    const unsigned short* A  = &Abuf[cur][0];
    const unsigned short* Bt = &Bbuf[cur][0];
    bf16x8 af[4], bfr[4];
#pragma unroll
    for (int t = 0; t < 4; ++t) {
      af[t]  = *(const bf16x8*)(A  + (wrow * 64 + t * 16 + r) * 32 + q * 8);
      bfr[t] = *(const bf16x8*)(Bt + (wcol * 64 + t * 16 + r) * 32 + q * 8);
    }
#pragma unroll
    for (int m = 0; m < 4; ++m)
#pragma unroll
      for (int n = 0; n < 4; ++n)
        acc[m][n] = MFMA(af[m], bfr[n], acc[m][n]);
  };

  loadA(aA, 0);
  stageB(0, 0);
  int ks = 0;
  while (true) {
    writeA(aA, ks & 1);
    __syncthreads();                            // A visible + stageB(ks) drained
    if (ks + 1 < 32) { stageB(ks + 1, (ks + 1) & 1); loadA(aB, ks + 1); }
    compute(ks & 1);
    if (++ks >= 32) break;
    writeA(aB, ks & 1);
    __syncthreads();
    if (ks + 1 < 32) { stageB(ks + 1, (ks + 1) & 1); loadA(aA, ks + 1); }
    compute(ks & 1);
    if (++ks >= 32) break;
  }

#pragma unroll
  for (int m = 0; m < 4; ++m) {
#pragma unroll
    for (int n = 0; n < 4; ++n) {
      const int e  = colB0 + wcol * 64 + n * 16 + r;
      const float bv = bias[e];
      const int h = e >> 6, dd = e & 63;
      const int nrow0 = rowA0 + wrow * 64 + m * 16 + q * 4;
      const int bb = nrow0 >> 11, ss0 = nrow0 & 2047;
      const size_t bh = (size_t)(bb * HEADS + h);
      if (z == 0) {
#pragma unroll
        for (int j = 0; j < 4; ++j)
          out[(bh * SEQ_ + (ss0 + j)) * DHEAD + dd] = f2bf((acc[m][n][j] + bv) * 0.125f);
      } else if (z == 1) {
#pragma unroll
        for (int j = 0; j < 4; ++j) {
          const int s = ss0 + j;
          const size_t off = (bh * 64 + (size_t)(s >> 5)) * 2048
                           + (size_t)(((dd >> 5) * 2 + ((s >> 4) & 1)) * 512)
                           + (size_t)(((((dd & 31) >> 3) << 4) + (s & 15)) * 8)
                           + (dd & 7);
          out[off] = f2bf(acc[m][n][j] + bv);
        }
      } else {
        // V: 8KB tile per 64 t, t' = 4*(t&15) + (t>>4)
#pragma unroll
        for (int j = 0; j < 4; ++j) {
          const int s = ss0 + j;
          const int tile64 = s >> 6, t = s & 63;
          const int tp = 4 * (t & 15) + (t >> 4);
          const int tc = tp >> 5, u = tp & 31;
          const int ln = ((u >> 3) << 4) | (dd & 15);
          const size_t off = (bh * 32 + (size_t)tile64) * 4096
                           + (size_t)(tc * 2048 + (dd >> 4) * 512 + ln * 8 + (u & 7));
          out[off] = f2bf(acc[m][n][j] + bv);
        }
      }
    }
  }
}

// -------------------------------------------------------------- attention ---
// (R10-proven kernel, verbatim.) 512 blocks x 256 thr (4 waves x 32 rows =
// 128-row tile). Each block: 17 contiguous iters = fh(T)=[0,T+1) of one tile
// + sh of its complement. Packed-bf16 lattice gather, b64 P-write with
// t'-permuted V, 3-ring + counted s_waitcnt vmcnt(12). fh writes raw O to
// d_out + pL0; sh writes pO1 + pL1; reduce merges.
struct ErSet { bf16x8 e[8]; };

__global__ __launch_bounds__(256, 2) void attn_kernel(
    const unsigned short* __restrict__ qb, const unsigned short* __restrict__ kt,
    const unsigned short* __restrict__ vt, const unsigned short* __restrict__ Er,
    float* __restrict__ out, float* __restrict__ pO1, float* __restrict__ pL) {
  __shared__ unsigned short k_lds[3][4096];     // 8KB/buf (2x 4KB frag tiles)
  __shared__ unsigned short v_lds[3][4096];     // 8KB/buf (one 64-t permuted tile)
  __shared__ unsigned short p_lds[4][32][68];   // [s][t'] b64-written P

  const int tid  = threadIdx.x;
  const int lane = tid & 63, wv = tid >> 6;     // 4 waves
  const int q = lane >> 4, r = lane & 15;

  const int lid = blockIdx.x;
  const int xcd = lid & 7, idx = lid >> 3;
  const int bh  = (xcd << 2) | (idx & 3);       // 4 bh pinned per XCD L2
  const int jb  = idx >> 2;                     // 0..15
  const int p = jb >> 1, role = jb & 1;
  const int bb = bh >> 4, hh = bh & 15;

  const unsigned short* qbh = qb + (size_t)bh * SEQ_ * DHEAD;
  const char* ktb = (const char*)(kt + (size_t)bh * 64 * 2048);
  const char* vtb = (const char*)(vt + (size_t)bh * 32 * 4096);
  const f32x4 zero4 = {0.f, 0.f, 0.f, 0.f};

  const char* sgbase = (wv < 2) ? ktb : vtb;
  char* sdst0 = (char*)((wv < 2) ? &k_lds[0][0] : &v_lds[0][0]);
  const int shalf = (wv & 1) * 4096;
  const int soff  = lane * 16;

  auto stageKV = [&](int it, int buf) {         // 4 vmem ops, always
    const char* src = sgbase + (size_t)it * 8192 + shalf + soff;
    char* dst = sdst0 + buf * 8192 + shalf;
#pragma unroll
    for (int c = 0; c < 4; ++c)
      __builtin_amdgcn_global_load_lds((const AS1 void*)(src + c * 1024),
                                       (AS3 void*)(dst + c * 1024), 16, 0, 0);
  };

  auto run_strip = [&](int T, int it0, int it1, float* po, float* pl) {
    const int s0 = T * 128 + wv * 32;
    __syncthreads();                            // drain prev strip
    stageKV(it0, 0);

    bf16x8 qf[2][2];
#pragma unroll
    for (int rt = 0; rt < 2; ++rt) {
      qf[rt][0] = *(const bf16x8*)(qbh + (size_t)(s0 + rt * 16 + r) * DHEAD + q * 8);
      qf[rt][1] = *(const bf16x8*)(qbh + (size_t)(s0 + rt * 16 + r) * DHEAD + 32 + q * 8);
    }

    f32x4 qer[2][6];
    {                                           // lattice init: tiles 0,1
      const int lb0 = 2016 + it0 * 64 - s0;
#pragma unroll
      for (int m = 0; m < 2; ++m) {
        int l = lb0 + m * 16 + r; l = l < 2047 ? l : 2047;
        bf16x8 e0 = *(const bf16x8*)(Er + (size_t)l * DHEAD + q * 8);
        bf16x8 e1 = *(const bf16x8*)(Er + (size_t)l * DHEAD + 32 + q * 8);
#pragma unroll
        for (int rt = 0; rt < 2; ++rt)
          qer[rt][m] = MFMA(qf[rt][1], e1, MFMA(qf[rt][0], e0, zero4));
      }
    }

    auto loadE = [&](ErSet& es, int it) {       // 8 vmem ops, always
      const int lb = 2016 + it * 64 - s0;
#pragma unroll
      for (int mi = 0; mi < 4; ++mi) {
        int l = lb + 32 + mi * 16 + r;
        l = l < 2047 ? l : 2047;
        es.e[mi * 2 + 0] = *(const bf16x8*)(Er + (size_t)l * DHEAD + q * 8);
        es.e[mi * 2 + 1] = *(const bf16x8*)(Er + (size_t)l * DHEAD + 32 + q * 8);
      }
    };

    f32x4 oacc[2][4] = {};
    float lpart[2][4] = {};

    auto body = [&](int it, int cur, const ErSet& es) {
      const int t0 = it * 64;
      if (t0 > s0 + 31) return;                 // masked tail (no barriers inside)
      const unsigned short* KL = &k_lds[cur][0];
      const unsigned short* VL = &v_lds[cur][0];

      bf16x8 kf[4][2];
#pragma unroll
      for (int ct = 0; ct < 4; ++ct)
#pragma unroll
        for (int kc = 0; kc < 2; ++kc)
          kf[ct][kc] = *(const bf16x8*)(KL + (ct >> 1) * 2048 + (kc * 2 + (ct & 1)) * 512 + lane * 8);

      f32x4 s4[2][4];
      __builtin_amdgcn_s_setprio(1);
#pragma unroll
      for (int rt = 0; rt < 2; ++rt)
#pragma unroll
        for (int ct = 0; ct < 4; ++ct)
          s4[rt][ct] = MFMA(qf[rt][1], kf[ct][1], MFMA(qf[rt][0], kf[ct][0], zero4));
#pragma unroll
      for (int rt = 0; rt < 2; ++rt)
#pragma unroll
        for (int mi = 0; mi < 4; ++mi)
          qer[rt][2 + mi] = MFMA(qf[rt][1], es.e[mi * 2 + 1],
                                 MFMA(qf[rt][0], es.e[mi * 2 + 0], zero4));
      __builtin_amdgcn_s_setprio(0);

      const int d0 = t0 - s0;
#pragma unroll
      for (int rt = 0; rt < 2; ++rt) {
        const int a = 1 - rt;                   // lattice window base tile
#pragma unroll
        for (int j = 0; j < 4; ++j) {
          unsigned int pkA = cvtpk(qer[rt][a][j],     qer[rt][a + 1][j]);
          unsigned int pkB = cvtpk(qer[rt][a + 2][j], qer[rt][a + 3][j]);
          const float  s5f = qer[rt][a + 4][j];
          const int srcl = (q << 4) | ((15 + r - q * 4 - j) & 15);
          unsigned int A = (unsigned int)__shfl((int)pkA, srcl);
          unsigned int B = (unsigned int)__shfl((int)pkB, srcl);
          const float g4 = __shfl(s5f, srcl);
          const float g0 = __builtin_bit_cast(float, A << 16);
          const float g1 = __builtin_bit_cast(float, A & 0xffff0000u);
          const float g2 = __builtin_bit_cast(float, B << 16);
          const float g3 = __builtin_bit_cast(float, B & 0xffff0000u);
          const bool hi = (r > q * 4 + j);
          const float b0 = hi ? g1 : g0;
          const float b1 = hi ? g2 : g1;
          const float b2 = hi ? g3 : g2;
          const float b3 = hi ? g4 : g3;
          const int A_ = rt * 16 + q * 4 + j - r - d0;   // keep iff ct*16 <= A_
          const float p0 = (A_ >= 0)  ? __expf(s4[rt][0][j] + b0) : 0.f;
          const float p1 = (A_ >= 16) ? __expf(s4[rt][1][j] + b1) : 0.f;
          const float p2 = (A_ >= 32) ? __expf(s4[rt][2][j] + b2) : 0.f;
          const float p3 = (A_ >= 48) ? __expf(s4[rt][3][j] + b3) : 0.f;
          lpart[rt][j] += (p0 + p1) + (p2 + p3);
          const int sl = rt * 16 + q * 4 + j;
          const unsigned long long pw =
              (unsigned long long)cvtpk(p0, p1) |
              ((unsigned long long)cvtpk(p2, p3) << 32);
          *(unsigned long long*)&p_lds[wv][sl][4 * r] = pw;   // t' = 4r+ct
        }
      }

      bf16x8 vf[4][2];
#pragma unroll
      for (int dc = 0; dc < 4; ++dc)
#pragma unroll
        for (int tc = 0; tc < 2; ++tc)
          vf[dc][tc] = *(const bf16x8*)(VL + tc * 2048 + dc * 512 + lane * 8);
      __builtin_amdgcn_s_setprio(1);
#pragma unroll
      for (int rt = 0; rt < 2; ++rt) {
        bf16x8 pf0 = *(const bf16x8*)(&p_lds[wv][rt * 16 + r][0] + q * 8);
        bf16x8 pf1 = *(const bf16x8*)(&p_lds[wv][rt * 16 + r][0] + 32 + q * 8);
#pragma unroll
        for (int dc = 0; dc < 4; ++dc)
          oacc[rt][dc] = MFMA(pf1, vf[dc][1], MFMA(pf0, vf[dc][0], oacc[rt][dc]));
      }
      __builtin_amdgcn_s_setprio(0);

#pragma unroll
      for (int rt = 0; rt < 2; ++rt) { qer[rt][0] = qer[rt][4]; qer[rt][1] = qer[rt][5]; }
    };

    ErSet eA, eB;
    loadE(eA, it0);

    int it = it0, cur = 0;
    while (true) {
      int nx = cur + 1; if (nx == 3) nx = 0;
      int itn = (it + 1 < it1) ? it + 1 : it1 - 1;
      stageKV(itn, nx);
      loadE(eB, itn);
      asm volatile("s_waitcnt vmcnt(12)\n\ts_barrier" ::: "memory");
      body(it, cur, eA);
      cur = nx;
      if (++it >= it1) break;
      nx = cur + 1; if (nx == 3) nx = 0;
      itn = (it + 1 < it1) ? it + 1 : it1 - 1;
      stageKV(itn, nx);
      loadE(eA, itn);
      asm volatile("s_waitcnt vmcnt(12)\n\ts_barrier" ::: "memory");
      body(it, cur, eB);
      cur = nx;
      if (++it >= it1) break;
    }

    // epilogue: partial sums (unnormalized)
#pragma unroll
    for (int rt = 0; rt < 2; ++rt)
#pragma unroll
      for (int j = 0; j < 4; ++j) {
        float ls = lpart[rt][j];
#pragma unroll
        for (int d = 1; d < 16; d <<= 1) ls += __shfl_xor(ls, d);
        const int row = wv * 32 + rt * 16 + q * 4 + j;
        if (po) {
#pragma unroll
          for (int dc = 0; dc < 4; ++dc)
            po[(size_t)row * 64 + dc * 16 + r] = oacc[rt][dc][j];
        } else {                                // fh: raw O into d_out
          const int ss = T * 128 + row;
#pragma unroll
          for (int dc = 0; dc < 4; ++dc)
            out[((size_t)(bb * SEQ_ + ss)) * DMODEL + hh * DHEAD + dc * 16 + r] = oacc[rt][dc][j];
        }
        if (r == 0) pl[row] = ls;
      }
  };

  // block = fh(TA) + sh(TB), 17 iters total
  int TA, a1, TB, b0, b1;
  if (role == 0) { TA = 15 - p; a1 = 16 - p; TB = p;      b0 = p + 1;  b1 = 2 * p + 2; }
  else           { TA = p;      a1 = p + 1;  TB = 15 - p; b0 = 16 - p; b1 = 32 - 2 * p; }

  run_strip(TA, 0, a1, nullptr,
            pL + ((size_t)(bh * 16 + TA)) * 256);
  run_strip(TB, b0, b1, pO1 + ((size_t)(bh * 16 + TB)) * 8192,
            pL + ((size_t)(bh * 16 + TB)) * 256 + 128);
}

// ---------------------------------------------------------------- reduce ----
// out = (out_fh + pO1_sh) / (l0 + l1) for every 128-row tile.
__global__ __launch_bounds__(256) void reduce_kernel(const float* __restrict__ pO1,
                                                     const float* __restrict__ pL,
                                                     float* __restrict__ out) {
  const int slot = blockIdx.x;                  // bh*16 + T
  const int bh = slot >> 4, T = slot & 15;
  const int bb = bh >> 4, hh = bh & 15;
  const int tid = threadIdx.x;
  const int row = tid >> 1, half = (tid & 1) * 32;

  const float l0 = pL[(size_t)slot * 256 + row];
  const float l1 = pL[(size_t)slot * 256 + 128 + row];
  const float inv = 1.0f / (l0 + l1);

  float* a = out + ((size_t)(bb * SEQ_) + T * 128 + row) * DMODEL + hh * DHEAD + half;
  const float* b = pO1 + (size_t)slot * 8192 + row * 64 + half;
#pragma unroll
  for (int k = 0; k < 8; ++k) {
    float4 x = ((const float4*)a)[k];
    float4 y = ((const float4*)b)[k];
    float4 o;
    o.x = (x.x + y.x) * inv; o.y = (x.y + y.y) * inv;
    o.z = (x.z + y.z) * inv; o.w = (x.w + y.w) * inv;
    ((float4*)a)[k] = o;
  }
}

// ------------------------------------------------------------------ launch ---
extern "C" void kernel_launch(void* const* d_in, const int* in_sizes, int n_in,
                              void* d_out, int out_size, void* d_ws, size_t ws_size,
                              hipStream_t stream) {
  const float* query = (const float*)d_in[0];
  const float* key   = (const float*)d_in[1];
  const float* value = (const float*)d_in[2];
  const float* Wq    = (const float*)d_in[3];
  const float* bq    = (const float*)d_in[4];
  const float* Wk    = (const float*)d_in[5];
  const float* bk    = (const float*)d_in[6];
  const float* Wv    = (const float*)d_in[7];
  const float* bv    = (const float*)d_in[8];
  const float* Er    = (const float*)d_in[9];

  char* ws = (char*)d_ws;
  unsigned short* qb   = (unsigned short*)(ws + (0u  << 20));  // 8MB
  unsigned short* ktil = (unsigned short*)(ws + (8u  << 20));  // 8MB
  unsigned short* vtil = (unsigned short*)(ws + (16u << 20));  // 8MB
  float*          pO1  = (float*)(ws + (24u << 20));           // 16MB [24,40)
  float*          pL   = (float*)(ws + (40u << 20));           // 512KB
  unsigned short* Wqb  = (unsigned short*)(ws + (56u << 20));  // 2MB
  unsigned short* Wkb  = (unsigned short*)(ws + (58u << 20));
  unsigned short* Wvb  = (unsigned short*)(ws + (60u << 20));
  unsigned short* Erb  = (unsigned short*)(ws + (62u << 20));  // 256KB

  conv4_kernel<<<dim3(512, 4), 256, 0, stream>>>(Wq, Wk, Wv, Er,
                                                 Wqb, Wkb, Wvb, Erb,
                                                 DMODEL * DMODEL, SEQ_ * DHEAD);

  proj3_kernel<<<dim3(32, 8, 3), 256, 0, stream>>>(query, key, value,
                                                   Wqb, Wkb, Wvb,
                                                   bq, bk, bv, qb, ktil, vtil);

  attn_kernel<<<dim3(512), 256, 0, stream>>>(qb, ktil, vtil, Erb,
                                             (float*)d_out, pO1, pL);

  reduce_kernel<<<dim3(512), 256, 0, stream>>>(pO1, pL, (float*)d_out);
}

// Round 13
// 152.957 us; speedup vs baseline: 1.5934x; 1.0512x over previous
//
#include <hip/hip_runtime.h>
#include <hip/hip_bf16.h>

typedef __attribute__((ext_vector_type(8))) short bf16x8;   // 8 bf16 = 4 VGPR (MFMA A/B frag)
typedef __attribute__((ext_vector_type(4))) float f32x4;    // MFMA C/D frag

#define DEVI __device__ __forceinline__
#define AS1 __attribute__((address_space(1)))
#define AS3 __attribute__((address_space(3)))

constexpr int SEQ_   = 2048;
constexpr int HEADS  = 16;
constexpr int DHEAD  = 64;
constexpr int DMODEL = 1024;

DEVI unsigned short f2bf(float x) {
  __hip_bfloat16 h = __float2bfloat16(x);   // RNE
  return __builtin_bit_cast(unsigned short, h);
}

DEVI f32x4 MFMA(bf16x8 a, bf16x8 b, f32x4 c) {
  return __builtin_amdgcn_mfma_f32_16x16x32_bf16(a, b, c, 0, 0, 0);
}

DEVI unsigned int cvtpk(float lo, float hi) {   // dst.lo16=bf16(lo), dst.hi16=bf16(hi)
  unsigned int u;
  asm("v_cvt_pk_bf16_f32 %0, %1, %2" : "=v"(u) : "v"(lo), "v"(hi));
  return u;
}

// ---------------------------------------------------------------- convert ---
__global__ void conv3_kernel(const float* s0, const float* s1, const float* s2,
                             unsigned short* d0, unsigned short* d1, unsigned short* d2,
                             int n) {
  const float* s = (blockIdx.y == 0) ? s0 : (blockIdx.y == 1) ? s1 : s2;
  unsigned short* d = (blockIdx.y == 0) ? d0 : (blockIdx.y == 1) ? d1 : d2;
  int i = (blockIdx.x * 256 + threadIdx.x) * 8;
  if (i >= n) return;
  const float4* p = (const float4*)(s + i);
  float4 v0 = p[0], v1 = p[1];
  union { unsigned short u[8]; bf16x8 v; } t;
  t.u[0] = f2bf(v0.x); t.u[1] = f2bf(v0.y); t.u[2] = f2bf(v0.z); t.u[3] = f2bf(v0.w);
  t.u[4] = f2bf(v1.x); t.u[5] = f2bf(v1.y); t.u[6] = f2bf(v1.z); t.u[7] = f2bf(v1.w);
  *(bf16x8*)(d + i) = t.v;
}

__global__ void conv4_kernel(const float* s0, const float* s1, const float* s2,
                             const float* s3,
                             unsigned short* d0, unsigned short* d1,
                             unsigned short* d2, unsigned short* d3,
                             int n_w, int n_e) {
  const int y = blockIdx.y;
  const float* s = (y == 0) ? s0 : (y == 1) ? s1 : (y == 2) ? s2 : s3;
  unsigned short* d = (y == 0) ? d0 : (y == 1) ? d1 : (y == 2) ? d2 : d3;
  const int n = (y == 3) ? n_e : n_w;
  int i = (blockIdx.x * 256 + threadIdx.x) * 8;
  if (i >= n) return;
  const float4* p = (const float4*)(s + i);
  float4 v0 = p[0], v1 = p[1];
  union { unsigned short u[8]; bf16x8 v; } t;
  t.u[0] = f2bf(v0.x); t.u[1] = f2bf(v0.y); t.u[2] = f2bf(v0.z); t.u[3] = f2bf(v0.w);
  t.u[4] = f2bf(v1.x); t.u[5] = f2bf(v1.y); t.u[6] = f2bf(v1.z); t.u[7] = f2bf(v1.w);
  *(bf16x8*)(d + i) = t.v;
}

// ------------------------------------------------------------- projection ---
// z==0 (Q): out (b,h,s,d), pre-scaled by 0.125*log2(e) (exp2 softmax fold).
// z==1 (K): 4KB tiles (per 32 t) in MFMA fragment order.
// z==2 (V): 4KB tiles (per 32 t) frag order with t' = 2*(t&15) + (t>>4)
//           (matches attn's b32 P-write order).
__global__ __launch_bounds__(256) void proj3_kernel(
    const unsigned short* __restrict__ X0, const unsigned short* __restrict__ X1,
    const unsigned short* __restrict__ X2,
    const unsigned short* __restrict__ W0, const unsigned short* __restrict__ W1,
    const unsigned short* __restrict__ W2,
    const float* __restrict__ bi0, const float* __restrict__ bi1,
    const float* __restrict__ bi2,
    unsigned short* __restrict__ o0, unsigned short* __restrict__ o1,
    unsigned short* __restrict__ o2) {
  const int z = blockIdx.z;
  const unsigned short* X = (z == 0) ? X0 : (z == 1) ? X1 : X2;
  const unsigned short* W = (z == 0) ? W0 : (z == 1) ? W1 : W2;
  const float* bias        = (z == 0) ? bi0 : (z == 1) ? bi1 : bi2;
  unsigned short* out      = (z == 0) ? o0 : (z == 1) ? o1 : o2;

  __shared__ unsigned short Abuf[2][128 * 32];
  __shared__ unsigned short Bbuf[2][128 * 32];
  const int tid  = threadIdx.x;
  const int lane = tid & 63, wv = tid >> 6;
  const int q = lane >> 4, r = lane & 15;
  const int wrow = wv >> 1, wcol = wv & 1;
  const int rowA0 = blockIdx.x * 128, colB0 = blockIdx.y * 128;

  const char* Ag = (const char*)(X + (size_t)rowA0 * DMODEL);
  const char* Bg = (const char*)(W + (size_t)colB0 * DMODEL);

  f32x4 acc[4][4] = {};

  auto stage = [&](int ks, int buf) {
    const int koff = ks * 64;
#pragma unroll
    for (int i = 0; i < 2; ++i) {
      const int b   = (i * 256 + tid) * 16;
      const int row = b >> 6, col = b & 63;
      __builtin_amdgcn_global_load_lds(
          (const AS1 void*)(Ag + (size_t)row * (DMODEL * 2) + koff + col),
          (AS3 void*)((char*)&Abuf[buf][0] + i * 4096 + wv * 1024),
          16, 0, 0);
      __builtin_amdgcn_global_load_lds(
          (const AS1 void*)(Bg + (size_t)row * (DMODEL * 2) + koff + col),
          (AS3 void*)((char*)&Bbuf[buf][0] + i * 4096 + wv * 1024),
          16, 0, 0);
    }
  };

  stage(0, 0);
  for (int ks = 0; ks < 32; ++ks) {
    __syncthreads();
    if (ks + 1 < 32) stage(ks + 1, (ks + 1) & 1);
    const unsigned short* A  = &Abuf[ks & 1][0];
    const unsigned short* Bt = &Bbuf[ks & 1][0];
    bf16x8 af[4], bfr[4];
#pragma unroll
    for (int t = 0; t < 4; ++t) {
      af[t]  = *(const bf16x8*)(A  + (wrow * 64 + t * 16 + r) * 32 + q * 8);
      bfr[t] = *(const bf16x8*)(Bt + (wcol * 64 + t * 16 + r) * 32 + q * 8);
    }
#pragma unroll
    for (int m = 0; m < 4; ++m)
#pragma unroll
      for (int n = 0; n < 4; ++n)
        acc[m][n] = MFMA(af[m], bfr[n], acc[m][n]);
  }

#pragma unroll
  for (int m = 0; m < 4; ++m) {
#pragma unroll
    for (int n = 0; n < 4; ++n) {
      const int e  = colB0 + wcol * 64 + n * 16 + r;
      const float bv = bias[e];
      const int h = e >> 6, dd = e & 63;
      const int nrow0 = rowA0 + wrow * 64 + m * 16 + q * 4;
      const int bb = nrow0 >> 11, ss0 = nrow0 & 2047;
      const size_t bh = (size_t)(bb * HEADS + h);
      if (z == 0) {
#pragma unroll
        for (int j = 0; j < 4; ++j)
          out[(bh * SEQ_ + (ss0 + j)) * DHEAD + dd] =
              f2bf((acc[m][n][j] + bv) * 0.1803368801111244f);   // 0.125*log2e
      } else if (z == 1) {
#pragma unroll
        for (int j = 0; j < 4; ++j) {
          const int s = ss0 + j;
          const size_t off = (bh * 64 + (size_t)(s >> 5)) * 2048
                           + (size_t)(((dd >> 5) * 2 + ((s >> 4) & 1)) * 512)
                           + (size_t)(((((dd & 31) >> 3) << 4) + (s & 15)) * 8)
                           + (dd & 7);
          out[off] = f2bf(acc[m][n][j] + bv);
        }
      } else {
        // V: 4KB tile per 32 t, t' = 2*(t&15) + (t>>4)
#pragma unroll
        for (int j = 0; j < 4; ++j) {
          const int s = ss0 + j;
          const int t = s & 31;
          const int tp = 2 * (t & 15) + (t >> 4);
          const size_t off = (bh * 64 + (size_t)(s >> 5)) * 2048
                           + (size_t)((dd >> 4) * 512)
                           + (size_t)(((((tp >> 3) << 4) | (dd & 15))) * 8)
                           + (tp & 7);
          out[off] = f2bf(acc[m][n][j] + bv);
        }
      }
    }
  }
}

// -------------------------------------------------------------- attention ---
// R11 logic (verified correct), launch_bounds(256,2): no forced VGPR cap ->
// no spill; LDS 34KB + VGPR ~100 should give 4 blocks/CU naturally.
// 1024 blocks x 256 thr (4 waves x 32 rows = 128-row tile). KVBLK=32,
// ring-3 LDS, counted s_waitcnt vmcnt(6) + raw s_barrier. Block (p,qq) runs
// quarter qq of tiles (15-p) and p = 17 iters, all blocks equal. 4 bf16
// partial slots per tile; reduce merges. exp2 softmax (log2e in Q). P via
// 1 cvt_pk b32 write/(rt,j); V t'-permuted; skew gather = 2 shuffles/(rt,j).
struct ErSet { bf16x8 e[4]; };                  // 2 fresh tiles x 2 kc

__global__ __launch_bounds__(256, 2) void attn_kernel(
    const unsigned short* __restrict__ qb, const unsigned short* __restrict__ kt,
    const unsigned short* __restrict__ vt, const unsigned short* __restrict__ Er,
    unsigned short* __restrict__ pO, float* __restrict__ pL) {
  __shared__ unsigned short k_lds[3][2048];     // 4KB/buf frag-order K tile
  __shared__ unsigned short v_lds[3][2048];     // 4KB/buf t'-permuted V tile
  __shared__ unsigned short p_lds[4][32][40];   // [s][t'] b32-written P (80B rows)

  const int tid  = threadIdx.x;
  const int lane = tid & 63, wv = tid >> 6;     // 4 waves
  const int q = lane >> 4, r = lane & 15;

  const int lid = blockIdx.x;
  const int xcd = lid & 7, idx = lid >> 3;      // 128 per XCD
  const int bh  = (xcd << 2) | (idx & 3);       // 4 bh pinned per XCD L2
  const int rest = idx >> 2;                    // 0..31
  const int p = rest >> 2, qq = rest & 3;       // pair p (0..7), quarter qq

  const unsigned short* qbh = qb + (size_t)bh * SEQ_ * DHEAD;
  const char* ktb = (const char*)(kt + (size_t)bh * 64 * 2048);
  const char* vtb = (const char*)(vt + (size_t)bh * 64 * 2048);
  const f32x4 zero4 = {0.f, 0.f, 0.f, 0.f};

  // staging roles: waves 0,1 -> K; waves 2,3 -> V; 2KB (2 x 1KB DMA) each
  const char* sgbase = (wv < 2) ? ktb : vtb;
  char* sdst0 = (char*)((wv < 2) ? &k_lds[0][0] : &v_lds[0][0]);
  const int shalf = (wv & 1) * 2048;
  const int soff  = lane * 16;

  auto stage = [&](int it, int buf) {           // 2 vmem ops / wave
    const char* src = sgbase + (size_t)it * 4096 + shalf + soff;
    char* dst = sdst0 + buf * 4096 + shalf;
    __builtin_amdgcn_global_load_lds((const AS1 void*)(src),
                                     (AS3 void*)(dst), 16, 0, 0);
    __builtin_amdgcn_global_load_lds((const AS1 void*)(src + 1024),
                                     (AS3 void*)(dst + 1024), 16, 0, 0);
  };

  auto run_strip = [&](int T, int it0, int it1, unsigned short* po, float* pl) {
    const int s0 = T * 128 + wv * 32;
    __syncthreads();                            // prev strip done with bufs
    stage(it0, 0);

    bf16x8 qf[2][2];
#pragma unroll
    for (int rt = 0; rt < 2; ++rt) {
      qf[rt][0] = *(const bf16x8*)(qbh + (size_t)(s0 + rt * 16 + r) * DHEAD + q * 8);
      qf[rt][1] = *(const bf16x8*)(qbh + (size_t)(s0 + rt * 16 + r) * DHEAD + 32 + q * 8);
    }

    // lattice qer[rt][m]: QEr[s0+rt*16+q*4+j][B0(it)+16m+r], window m=0..3
    f32x4 qer[2][4];
    {
      const int B0 = 2016 + 32 * it0 - s0;
#pragma unroll
      for (int m = 0; m < 2; ++m) {
        int l = B0 + m * 16 + r; l = l < 2047 ? l : 2047;
        bf16x8 e0 = *(const bf16x8*)(Er + (size_t)l * DHEAD + q * 8);
        bf16x8 e1 = *(const bf16x8*)(Er + (size_t)l * DHEAD + 32 + q * 8);
#pragma unroll
        for (int rt = 0; rt < 2; ++rt)
          qer[rt][m] = MFMA(qf[rt][1], e1, MFMA(qf[rt][0], e0, zero4));
      }
    }

    auto loadE = [&](ErSet& es, int it) {       // 4 vmem ops / wave
      const int B0 = 2016 + 32 * it - s0;
#pragma unroll
      for (int mi = 0; mi < 2; ++mi) {
        int l = B0 + 32 + mi * 16 + r;
        l = l < 2047 ? l : 2047;                // clamped rows feed masked cols
        es.e[mi * 2 + 0] = *(const bf16x8*)(Er + (size_t)l * DHEAD + q * 8);
        es.e[mi * 2 + 1] = *(const bf16x8*)(Er + (size_t)l * DHEAD + 32 + q * 8);
      }
    };

    f32x4 oacc[2][4] = {};
    float lpart[2][4] = {};

    auto body = [&](int it, int cur, const ErSet& es) {
      const int t0 = it * 32;
      if (t0 > s0 + 31) return;                 // masked tail (wave-uniform)
      const unsigned short* KL = &k_lds[cur][0];
      const unsigned short* VL = &v_lds[cur][0];

      bf16x8 kf[2][2];
#pragma unroll
      for (int ct = 0; ct < 2; ++ct)
#pragma unroll
        for (int kc = 0; kc < 2; ++kc)
          kf[ct][kc] = *(const bf16x8*)(KL + (kc * 2 + ct) * 512 + lane * 8);

      f32x4 s4[2][2];
      __builtin_amdgcn_s_setprio(1);
#pragma unroll
      for (int rt = 0; rt < 2; ++rt)
#pragma unroll
        for (int ct = 0; ct < 2; ++ct)
          s4[rt][ct] = MFMA(qf[rt][1], kf[ct][1], MFMA(qf[rt][0], kf[ct][0], zero4));
#pragma unroll
      for (int rt = 0; rt < 2; ++rt)
#pragma unroll
        for (int mi = 0; mi < 2; ++mi)
          qer[rt][2 + mi] = MFMA(qf[rt][1], es.e[mi * 2 + 1],
                                 MFMA(qf[rt][0], es.e[mi * 2 + 0], zero4));
      __builtin_amdgcn_s_setprio(0);

      const int d0 = t0 - s0;
#pragma unroll
      for (int rt = 0; rt < 2; ++rt) {
        const int a = 1 - rt;                   // window base tile
#pragma unroll
        for (int j = 0; j < 4; ++j) {
          const unsigned int pk = cvtpk(qer[rt][a][j], qer[rt][a + 1][j]);
          const float f2 = qer[rt][a + 2][j];
          const int srcl = (q << 4) | ((15 + r - q * 4 - j) & 15);
          const unsigned int A = (unsigned int)__shfl((int)pk, srcl);
          const float g2 = __shfl(f2, srcl);
          const float g0 = __builtin_bit_cast(float, A << 16);
          const float g1 = __builtin_bit_cast(float, A & 0xffff0000u);
          const bool hi = (r > q * 4 + j);
          const float b0 = hi ? g1 : g0;
          const float b1 = hi ? g2 : g1;
          const int A_ = rt * 16 + q * 4 + j - r - d0;   // keep iff ct*16 <= A_
          const float p0 = (A_ >= 0)  ? exp2f(s4[rt][0][j] + b0) : 0.f;
          const float p1 = (A_ >= 16) ? exp2f(s4[rt][1][j] + b1) : 0.f;
          lpart[rt][j] += p0 + p1;
          const int sl = rt * 16 + q * 4 + j;
          *(unsigned int*)&p_lds[wv][sl][2 * r] = cvtpk(p0, p1);   // t' = 2r+ct
        }
      }

      bf16x8 vf[4];
#pragma unroll
      for (int dc = 0; dc < 4; ++dc)
        vf[dc] = *(const bf16x8*)(VL + dc * 512 + lane * 8);
      __builtin_amdgcn_s_setprio(1);
#pragma unroll
      for (int rt = 0; rt < 2; ++rt) {
        bf16x8 pf = *(const bf16x8*)(&p_lds[wv][rt * 16 + r][0] + q * 8);
#pragma unroll
        for (int dc = 0; dc < 4; ++dc)
          oacc[rt][dc] = MFMA(pf, vf[dc], oacc[rt][dc]);
      }
      __builtin_amdgcn_s_setprio(0);

#pragma unroll
      for (int rt = 0; rt < 2; ++rt) { qer[rt][0] = qer[rt][2]; qer[rt][1] = qer[rt][3]; }
    };

    ErSet eA, eB;
    loadE(eA, it0);

    int it = it0, cur = 0;
    while (true) {
      int nx = cur + 1; if (nx == 3) nx = 0;
      int itn = (it + 1 < it1) ? it + 1 : it1 - 1;
      stage(itn, nx);
      loadE(eB, itn);
      asm volatile("s_waitcnt vmcnt(6)\n\ts_barrier" ::: "memory");
      body(it, cur, eA);
      cur = nx;
      if (++it >= it1) break;
      nx = cur + 1; if (nx == 3) nx = 0;
      itn = (it + 1 < it1) ? it + 1 : it1 - 1;
      stage(itn, nx);
      loadE(eA, itn);
      asm volatile("s_waitcnt vmcnt(6)\n\ts_barrier" ::: "memory");
      body(it, cur, eB);
      cur = nx;
      if (++it >= it1) break;
    }

    // epilogue: bf16 partial O + f32 partial l (unnormalized)
#pragma unroll
    for (int rt = 0; rt < 2; ++rt)
#pragma unroll
      for (int j = 0; j < 4; ++j) {
        float ls = lpart[rt][j];
#pragma unroll
        for (int d = 1; d < 16; d <<= 1) ls += __shfl_xor(ls, d);
        const int row = wv * 32 + rt * 16 + q * 4 + j;
#pragma unroll
        for (int dc = 0; dc < 4; ++dc)
          po[(size_t)row * 64 + dc * 16 + r] = f2bf(oacc[rt][dc][j]);
        if (r == 0) pl[row] = ls;
      }
  };

  const int TA = 15 - p, lenA = 16 - p;         // big tile: 64-4p iters = 4*lenA
  const int TB = p,      lenB = p + 1;          // small tile: 4p+4 iters = 4*lenB
  const size_t slotA = ((size_t)bh * 16 + TA) * 4 + qq;
  const size_t slotB = ((size_t)bh * 16 + TB) * 4 + qq;

  run_strip(TA, qq * lenA, (qq + 1) * lenA, pO + slotA * 8192, pL + slotA * 128);
  run_strip(TB, qq * lenB, (qq + 1) * lenB, pO + slotB * 8192, pL + slotB * 128);
}

// ---------------------------------------------------------------- reduce ----
// out = sum(4 bf16 partial O) / sum(4 partial l) per 128-row tile.
__global__ __launch_bounds__(256) void reduce_kernel(const unsigned short* __restrict__ pO,
                                                     const float* __restrict__ pL,
                                                     float* __restrict__ out) {
  const int slot = blockIdx.x;                  // bh*16 + T
  const int bh = slot >> 4, T = slot & 15;
  const int bb = bh >> 4, hh = bh & 15;
  const int tid = threadIdx.x;
  const int row = tid >> 1, half = (tid & 1) * 32;

  float l = 0.f;
#pragma unroll
  for (int k = 0; k < 4; ++k) l += pL[((size_t)slot * 4 + k) * 128 + row];
  const float inv = 1.0f / l;

  float acc[32] = {};
#pragma unroll
  for (int k = 0; k < 4; ++k) {
    const unsigned short* src = pO + ((size_t)slot * 4 + k) * 8192 + row * 64 + half;
#pragma unroll
    for (int c = 0; c < 4; ++c) {
      union { bf16x8 v; unsigned short u[8]; } w;
      w.v = *(const bf16x8*)(src + c * 8);
#pragma unroll
      for (int e = 0; e < 8; ++e)
        acc[c * 8 + e] += __builtin_bit_cast(float, (unsigned int)w.u[e] << 16);
    }
  }

  float* dst = out + ((size_t)(bb * SEQ_) + T * 128 + row) * DMODEL + hh * DHEAD + half;
#pragma unroll
  for (int c = 0; c < 8; ++c) {
    float4 o;
    o.x = acc[c * 4 + 0] * inv; o.y = acc[c * 4 + 1] * inv;
    o.z = acc[c * 4 + 2] * inv; o.w = acc[c * 4 + 3] * inv;
    ((float4*)dst)[c] = o;
  }
}

// ------------------------------------------------------------------ launch ---
extern "C" void kernel_launch(void* const* d_in, const int* in_sizes, int n_in,
                              void* d_out, int out_size, void* d_ws, size_t ws_size,
                              hipStream_t stream) {
  const float* query = (const float*)d_in[0];
  const float* key   = (const float*)d_in[1];
  const float* value = (const float*)d_in[2];
  const float* Wq    = (const float*)d_in[3];
  const float* bq    = (const float*)d_in[4];
  const float* Wk    = (const float*)d_in[5];
  const float* bk    = (const float*)d_in[6];
  const float* Wv    = (const float*)d_in[7];
  const float* bv    = (const float*)d_in[8];
  const float* Er    = (const float*)d_in[9];

  char* ws = (char*)d_ws;
  unsigned short* qb   = (unsigned short*)(ws + (0u  << 20));  // 8MB
  unsigned short* ktil = (unsigned short*)(ws + (8u  << 20));  // 8MB
  unsigned short* vtil = (unsigned short*)(ws + (16u << 20));  // 8MB
  unsigned short* pO   = (unsigned short*)(ws + (24u << 20));  // 32MB bf16 [24,56)
  float*          pL   = (float*)(ws + (56u << 20));           // 1MB (Wqb dead post-proj)
  unsigned short* Xq   = (unsigned short*)(ws + (32u << 20));  // proj inputs (pre-attn only)
  unsigned short* Xk   = (unsigned short*)(ws + (40u << 20));
  unsigned short* Xv   = (unsigned short*)(ws + (48u << 20));
  unsigned short* Wqb  = (unsigned short*)(ws + (56u << 20));  // 2MB (clobbered by pL post-use)
  unsigned short* Wkb  = (unsigned short*)(ws + (58u << 20));
  unsigned short* Wvb  = (unsigned short*)(ws + (60u << 20));
  unsigned short* Erb  = (unsigned short*)(ws + (62u << 20));  // 256KB

  conv3_kernel<<<dim3(2048, 3), 256, 0, stream>>>(query, key, value, Xq, Xk, Xv,
                                                  2 * SEQ_ * DMODEL);
  conv4_kernel<<<dim3(512, 4), 256, 0, stream>>>(Wq, Wk, Wv, Er,
                                                 Wqb, Wkb, Wvb, Erb,
                                                 DMODEL * DMODEL, SEQ_ * DHEAD);

  proj3_kernel<<<dim3(32, 8, 3), 256, 0, stream>>>(Xq, Xk, Xv, Wqb, Wkb, Wvb,
                                                   bq, bk, bv, qb, ktil, vtil);

  attn_kernel<<<dim3(1024), 256, 0, stream>>>(qb, ktil, vtil, Erb, pO, pL);

  reduce_kernel<<<dim3(512), 256, 0, stream>>>(pO, pL, (float*)d_out);
}

// Round 14
// 147.778 us; speedup vs baseline: 1.6492x; 1.0350x over previous
//
#include <hip/hip_runtime.h>
#include <hip/hip_bf16.h>

typedef __attribute__((ext_vector_type(8))) short bf16x8;   // 8 bf16 = 4 VGPR (MFMA A/B frag)
typedef __attribute__((ext_vector_type(4))) float f32x4;    // MFMA C/D frag

#define DEVI __device__ __forceinline__
#define AS1 __attribute__((address_space(1)))
#define AS3 __attribute__((address_space(3)))

constexpr int SEQ_   = 2048;
constexpr int HEADS  = 16;
constexpr int DHEAD  = 64;
constexpr int DMODEL = 1024;

DEVI unsigned short f2bf(float x) {
  __hip_bfloat16 h = __float2bfloat16(x);   // RNE
  return __builtin_bit_cast(unsigned short, h);
}

DEVI f32x4 MFMA(bf16x8 a, bf16x8 b, f32x4 c) {
  return __builtin_amdgcn_mfma_f32_16x16x32_bf16(a, b, c, 0, 0, 0);
}

DEVI unsigned int cvtpk(float lo, float hi) {   // dst.lo16=bf16(lo), dst.hi16=bf16(hi)
  unsigned int u;
  asm("v_cvt_pk_bf16_f32 %0, %1, %2" : "=v"(u) : "v"(lo), "v"(hi));
  return u;
}

// ---------------------------------------------------------------- convert ---
// weights (y=0..2) + Er (y=3). X conversions are fused into proj3 (reg-staged).
__global__ void conv4_kernel(const float* s0, const float* s1, const float* s2,
                             const float* s3,
                             unsigned short* d0, unsigned short* d1,
                             unsigned short* d2, unsigned short* d3,
                             int n_w, int n_e) {
  const int y = blockIdx.y;
  const float* s = (y == 0) ? s0 : (y == 1) ? s1 : (y == 2) ? s2 : s3;
  unsigned short* d = (y == 0) ? d0 : (y == 1) ? d1 : (y == 2) ? d2 : d3;
  const int n = (y == 3) ? n_e : n_w;
  int i = (blockIdx.x * 256 + threadIdx.x) * 8;
  if (i >= n) return;
  const float4* p = (const float4*)(s + i);
  float4 v0 = p[0], v1 = p[1];
  union { unsigned short u[8]; bf16x8 v; } t;
  t.u[0] = f2bf(v0.x); t.u[1] = f2bf(v0.y); t.u[2] = f2bf(v0.z); t.u[3] = f2bf(v0.w);
  t.u[4] = f2bf(v1.x); t.u[5] = f2bf(v1.y); t.u[6] = f2bf(v1.z); t.u[7] = f2bf(v1.w);
  *(bf16x8*)(d + i) = t.v;
}

// ------------------------------------------------------------- projection ---
// A-side: fp32 X read directly (conv fused). Fixes vs R12: (a) LINEAR
// 16B/lane LDS writes (2 sub-tiles of 4KB) -> zero write conflicts;
// (b) loadA issued BEFORE __syncthreads (memory fence) -> cannot be sunk,
// latency hides under barrier+stageB+compute. B-side unchanged
// (global_load_lds). z==0 (Q): (b,h,s,d) pre-scaled 0.125. z==1 (K): 4KB
// frag-order tiles. z==2 (V): 8KB tiles, t' = 4*(t&15)+(t>>4).
__global__ __launch_bounds__(256) void proj3_kernel(
    const float* __restrict__ X0, const float* __restrict__ X1,
    const float* __restrict__ X2,
    const unsigned short* __restrict__ W0, const unsigned short* __restrict__ W1,
    const unsigned short* __restrict__ W2,
    const float* __restrict__ bi0, const float* __restrict__ bi1,
    const float* __restrict__ bi2,
    unsigned short* __restrict__ o0, unsigned short* __restrict__ o1,
    unsigned short* __restrict__ o2) {
  const int z = blockIdx.z;
  const float* X = (z == 0) ? X0 : (z == 1) ? X1 : X2;
  const unsigned short* W = (z == 0) ? W0 : (z == 1) ? W1 : W2;
  const float* bias        = (z == 0) ? bi0 : (z == 1) ? bi1 : bi2;
  unsigned short* out      = (z == 0) ? o0 : (z == 1) ? o1 : o2;

  __shared__ unsigned short Abuf[2][128 * 32];
  __shared__ unsigned short Bbuf[2][128 * 32];
  const int tid  = threadIdx.x;
  const int lane = tid & 63, wv = tid >> 6;
  const int q = lane >> 4, r = lane & 15;
  const int wrow = wv >> 1, wcol = wv & 1;
  const int rowA0 = blockIdx.x * 128, colB0 = blockIdx.y * 128;

  const float* Ag = X + (size_t)rowA0 * DMODEL;
  const char*  Bg = (const char*)(W + (size_t)colB0 * DMODEL);

  // A: thread t covers rows (t>>2)+c*64, shorts (t&3)*8..+8 (c=0,1)
  const int ar = tid >> 2, ac = (tid & 3) * 8;
  const float* Asrc = Ag + (size_t)ar * DMODEL + ac;
  unsigned short* Adst = &Abuf[0][0] + tid * 8;     // bytes t*16, linear

  float4 aA[4], aB[4];
  auto loadA = [&](float4* a4, int ks) {
    const float4* s0 = (const float4*)(Asrc + ks * 32);
    const float4* s1 = (const float4*)(Asrc + 64 * DMODEL + ks * 32);
    a4[0] = s0[0]; a4[1] = s0[1];
    a4[2] = s1[0]; a4[3] = s1[1];
  };
  auto writeA = [&](const float4* a4, int buf) {
    union { unsigned int u[4]; bf16x8 v; } p0, p1;
    p0.u[0] = cvtpk(a4[0].x, a4[0].y); p0.u[1] = cvtpk(a4[0].z, a4[0].w);
    p0.u[2] = cvtpk(a4[1].x, a4[1].y); p0.u[3] = cvtpk(a4[1].z, a4[1].w);
    p1.u[0] = cvtpk(a4[2].x, a4[2].y); p1.u[1] = cvtpk(a4[2].z, a4[2].w);
    p1.u[2] = cvtpk(a4[3].x, a4[3].y); p1.u[3] = cvtpk(a4[3].z, a4[3].w);
    *(bf16x8*)(Adst + buf * (128 * 32))        = p0.v;   // sub-tile 0 (rows 0-63)
    *(bf16x8*)(Adst + buf * (128 * 32) + 2048) = p1.v;   // sub-tile 1 (rows 64-127)
  };
  auto stageB = [&](int ks, int buf) {
    const int koff = ks * 64;
#pragma unroll
    for (int i = 0; i < 2; ++i) {
      const int b   = (i * 256 + tid) * 16;
      const int row = b >> 6, col = b & 63;
      __builtin_amdgcn_global_load_lds(
          (const AS1 void*)(Bg + (size_t)row * (DMODEL * 2) + koff + col),
          (AS3 void*)((char*)&Bbuf[buf][0] + i * 4096 + wv * 1024),
          16, 0, 0);
    }
  };

  f32x4 acc[4][4] = {};

  auto compute = [&](int cur) {
    const unsigned short* A  = &Abuf[cur][0];
    const unsigned short* Bt = &Bbuf[cur][0];
    bf16x8 af[4], bfr[4];
#pragma unroll
    for (int t = 0; t < 4; ++t) {
      af[t]  = *(const bf16x8*)(A  + (wrow * 64 + t * 16 + r) * 32 + q * 8);
      bfr[t] = *(const bf16x8*)(Bt + (wcol * 64 + t * 16 + r) * 32 + q * 8);
    }
#pragma unroll
    for (int m = 0; m < 4; ++m)
#pragma unroll
      for (int n = 0; n < 4; ++n)
        acc[m][n] = MFMA(af[m], bfr[n], acc[m][n]);
  };

  loadA(aA, 0);
  stageB(0, 0);
  int ks = 0;
  while (true) {
    writeA(aA, ks & 1);
    if (ks + 1 < 32) loadA(aB, ks + 1);        // pre-barrier: cannot sink
    __syncthreads();                            // stageB(ks) drained; A visible
    if (ks + 1 < 32) stageB(ks + 1, (ks + 1) & 1);
    compute(ks & 1);
    if (++ks >= 32) break;
    writeA(aB, ks & 1);
    if (ks + 1 < 32) loadA(aA, ks + 1);
    __syncthreads();
    if (ks + 1 < 32) stageB(ks + 1, (ks + 1) & 1);
    compute(ks & 1);
    if (++ks >= 32) break;
  }

#pragma unroll
  for (int m = 0; m < 4; ++m) {
#pragma unroll
    for (int n = 0; n < 4; ++n) {
      const int e  = colB0 + wcol * 64 + n * 16 + r;
      const float bv = bias[e];
      const int h = e >> 6, dd = e & 63;
      const int nrow0 = rowA0 + wrow * 64 + m * 16 + q * 4;
      const int bb = nrow0 >> 11, ss0 = nrow0 & 2047;
      const size_t bh = (size_t)(bb * HEADS + h);
      if (z == 0) {
#pragma unroll
        for (int j = 0; j < 4; ++j)
          out[(bh * SEQ_ + (ss0 + j)) * DHEAD + dd] = f2bf((acc[m][n][j] + bv) * 0.125f);
      } else if (z == 1) {
#pragma unroll
        for (int j = 0; j < 4; ++j) {
          const int s = ss0 + j;
          const size_t off = (bh * 64 + (size_t)(s >> 5)) * 2048
                           + (size_t)(((dd >> 5) * 2 + ((s >> 4) & 1)) * 512)
                           + (size_t)(((((dd & 31) >> 3) << 4) + (s & 15)) * 8)
                           + (dd & 7);
          out[off] = f2bf(acc[m][n][j] + bv);
        }
      } else {
        // V: 8KB tile per 64 t, t' = 4*(t&15) + (t>>4)
#pragma unroll
        for (int j = 0; j < 4; ++j) {
          const int s = ss0 + j;
          const int tile64 = s >> 6, t = s & 63;
          const int tp = 4 * (t & 15) + (t >> 4);
          const int tc = tp >> 5, u = tp & 31;
          const int ln = ((u >> 3) << 4) | (dd & 15);
          const size_t off = (bh * 32 + (size_t)tile64) * 4096
                           + (size_t)(tc * 2048 + (dd >> 4) * 512 + ln * 8 + (u & 7));
          out[off] = f2bf(acc[m][n][j] + bv);
        }
      }
    }
  }
}

// -------------------------------------------------------------- attention ---
// (R10-proven kernel, verbatim — 67.8us, conflicts=0.) 512 blocks x 256 thr
// (4 waves x 32 rows = 128-row tile). Each block: 17 contiguous iters =
// fh(T)=[0,T+1) of one tile + sh of its complement. Packed-bf16 lattice
// gather, b64 P-write with t'-permuted V, 3-ring + counted vmcnt(12).
// fh writes raw O to d_out + pL0; sh writes pO1 + pL1; reduce merges.
struct ErSet { bf16x8 e[8]; };

__global__ __launch_bounds__(256, 2) void attn_kernel(
    const unsigned short* __restrict__ qb, const unsigned short* __restrict__ kt,
    const unsigned short* __restrict__ vt, const unsigned short* __restrict__ Er,
    float* __restrict__ out, float* __restrict__ pO1, float* __restrict__ pL) {
  __shared__ unsigned short k_lds[3][4096];     // 8KB/buf (2x 4KB frag tiles)
  __shared__ unsigned short v_lds[3][4096];     // 8KB/buf (one 64-t permuted tile)
  __shared__ unsigned short p_lds[4][32][68];   // [s][t'] b64-written P

  const int tid  = threadIdx.x;
  const int lane = tid & 63, wv = tid >> 6;     // 4 waves
  const int q = lane >> 4, r = lane & 15;

  const int lid = blockIdx.x;
  const int xcd = lid & 7, idx = lid >> 3;
  const int bh  = (xcd << 2) | (idx & 3);       // 4 bh pinned per XCD L2
  const int jb  = idx >> 2;                     // 0..15
  const int p = jb >> 1, role = jb & 1;
  const int bb = bh >> 4, hh = bh & 15;

  const unsigned short* qbh = qb + (size_t)bh * SEQ_ * DHEAD;
  const char* ktb = (const char*)(kt + (size_t)bh * 64 * 2048);
  const char* vtb = (const char*)(vt + (size_t)bh * 32 * 4096);
  const f32x4 zero4 = {0.f, 0.f, 0.f, 0.f};

  const char* sgbase = (wv < 2) ? ktb : vtb;
  char* sdst0 = (char*)((wv < 2) ? &k_lds[0][0] : &v_lds[0][0]);
  const int shalf = (wv & 1) * 4096;
  const int soff  = lane * 16;

  auto stageKV = [&](int it, int buf) {         // 4 vmem ops, always
    const char* src = sgbase + (size_t)it * 8192 + shalf + soff;
    char* dst = sdst0 + buf * 8192 + shalf;
#pragma unroll
    for (int c = 0; c < 4; ++c)
      __builtin_amdgcn_global_load_lds((const AS1 void*)(src + c * 1024),
                                       (AS3 void*)(dst + c * 1024), 16, 0, 0);
  };

  auto run_strip = [&](int T, int it0, int it1, float* po, float* pl) {
    const int s0 = T * 128 + wv * 32;
    __syncthreads();                            // drain prev strip
    stageKV(it0, 0);

    bf16x8 qf[2][2];
#pragma unroll
    for (int rt = 0; rt < 2; ++rt) {
      qf[rt][0] = *(const bf16x8*)(qbh + (size_t)(s0 + rt * 16 + r) * DHEAD + q * 8);
      qf[rt][1] = *(const bf16x8*)(qbh + (size_t)(s0 + rt * 16 + r) * DHEAD + 32 + q * 8);
    }

    f32x4 qer[2][6];
    {                                           // lattice init: tiles 0,1
      const int lb0 = 2016 + it0 * 64 - s0;
#pragma unroll
      for (int m = 0; m < 2; ++m) {
        int l = lb0 + m * 16 + r; l = l < 2047 ? l : 2047;
        bf16x8 e0 = *(const bf16x8*)(Er + (size_t)l * DHEAD + q * 8);
        bf16x8 e1 = *(const bf16x8*)(Er + (size_t)l * DHEAD + 32 + q * 8);
#pragma unroll
        for (int rt = 0; rt < 2; ++rt)
          qer[rt][m] = MFMA(qf[rt][1], e1, MFMA(qf[rt][0], e0, zero4));
      }
    }

    auto loadE = [&](ErSet& es, int it) {       // 8 vmem ops, always
      const int lb = 2016 + it * 64 - s0;
#pragma unroll
      for (int mi = 0; mi < 4; ++mi) {
        int l = lb + 32 + mi * 16 + r;
        l = l < 2047 ? l : 2047;
        es.e[mi * 2 + 0] = *(const bf16x8*)(Er + (size_t)l * DHEAD + q * 8);
        es.e[mi * 2 + 1] = *(const bf16x8*)(Er + (size_t)l * DHEAD + 32 + q * 8);
      }
    };

    f32x4 oacc[2][4] = {};
    float lpart[2][4] = {};

    auto body = [&](int it, int cur, const ErSet& es) {
      const int t0 = it * 64;
      if (t0 > s0 + 31) return;                 // masked tail (no barriers inside)
      const unsigned short* KL = &k_lds[cur][0];
      const unsigned short* VL = &v_lds[cur][0];

      bf16x8 kf[4][2];
#pragma unroll
      for (int ct = 0; ct < 4; ++ct)
#pragma unroll
        for (int kc = 0; kc < 2; ++kc)
          kf[ct][kc] = *(const bf16x8*)(KL + (ct >> 1) * 2048 + (kc * 2 + (ct & 1)) * 512 + lane * 8);

      f32x4 s4[2][4];
      __builtin_amdgcn_s_setprio(1);
#pragma unroll
      for (int rt = 0; rt < 2; ++rt)
#pragma unroll
        for (int ct = 0; ct < 4; ++ct)
          s4[rt][ct] = MFMA(qf[rt][1], kf[ct][1], MFMA(qf[rt][0], kf[ct][0], zero4));
#pragma unroll
      for (int rt = 0; rt < 2; ++rt)
#pragma unroll
        for (int mi = 0; mi < 4; ++mi)
          qer[rt][2 + mi] = MFMA(qf[rt][1], es.e[mi * 2 + 1],
                                 MFMA(qf[rt][0], es.e[mi * 2 + 0], zero4));
      __builtin_amdgcn_s_setprio(0);

      const int d0 = t0 - s0;
#pragma unroll
      for (int rt = 0; rt < 2; ++rt) {
        const int a = 1 - rt;                   // lattice window base tile
#pragma unroll
        for (int j = 0; j < 4; ++j) {
          unsigned int pkA = cvtpk(qer[rt][a][j],     qer[rt][a + 1][j]);
          unsigned int pkB = cvtpk(qer[rt][a + 2][j], qer[rt][a + 3][j]);
          const float  s5f = qer[rt][a + 4][j];
          const int srcl = (q << 4) | ((15 + r - q * 4 - j) & 15);
          unsigned int A = (unsigned int)__shfl((int)pkA, srcl);
          unsigned int B = (unsigned int)__shfl((int)pkB, srcl);
          const float g4 = __shfl(s5f, srcl);
          const float g0 = __builtin_bit_cast(float, A << 16);
          const float g1 = __builtin_bit_cast(float, A & 0xffff0000u);
          const float g2 = __builtin_bit_cast(float, B << 16);
          const float g3 = __builtin_bit_cast(float, B & 0xffff0000u);
          const bool hi = (r > q * 4 + j);
          const float b0 = hi ? g1 : g0;
          const float b1 = hi ? g2 : g1;
          const float b2 = hi ? g3 : g2;
          const float b3 = hi ? g4 : g3;
          const int A_ = rt * 16 + q * 4 + j - r - d0;   // keep iff ct*16 <= A_
          const float p0 = (A_ >= 0)  ? __expf(s4[rt][0][j] + b0) : 0.f;
          const float p1 = (A_ >= 16) ? __expf(s4[rt][1][j] + b1) : 0.f;
          const float p2 = (A_ >= 32) ? __expf(s4[rt][2][j] + b2) : 0.f;
          const float p3 = (A_ >= 48) ? __expf(s4[rt][3][j] + b3) : 0.f;
          lpart[rt][j] += (p0 + p1) + (p2 + p3);
          const int sl = rt * 16 + q * 4 + j;
          const unsigned long long pw =
              (unsigned long long)cvtpk(p0, p1) |
              ((unsigned long long)cvtpk(p2, p3) << 32);
          *(unsigned long long*)&p_lds[wv][sl][4 * r] = pw;   // t' = 4r+ct
        }
      }

      bf16x8 vf[4][2];
#pragma unroll
      for (int dc = 0; dc < 4; ++dc)
#pragma unroll
        for (int tc = 0; tc < 2; ++tc)
          vf[dc][tc] = *(const bf16x8*)(VL + tc * 2048 + dc * 512 + lane * 8);
      __builtin_amdgcn_s_setprio(1);
#pragma unroll
      for (int rt = 0; rt < 2; ++rt) {
        bf16x8 pf0 = *(const bf16x8*)(&p_lds[wv][rt * 16 + r][0] + q * 8);
        bf16x8 pf1 = *(const bf16x8*)(&p_lds[wv][rt * 16 + r][0] + 32 + q * 8);
#pragma unroll
        for (int dc = 0; dc < 4; ++dc)
          oacc[rt][dc] = MFMA(pf1, vf[dc][1], MFMA(pf0, vf[dc][0], oacc[rt][dc]));
      }
      __builtin_amdgcn_s_setprio(0);

#pragma unroll
      for (int rt = 0; rt < 2; ++rt) { qer[rt][0] = qer[rt][4]; qer[rt][1] = qer[rt][5]; }
    };

    ErSet eA, eB;
    loadE(eA, it0);

    int it = it0, cur = 0;
    while (true) {
      int nx = cur + 1; if (nx == 3) nx = 0;
      int itn = (it + 1 < it1) ? it + 1 : it1 - 1;
      stageKV(itn, nx);
      loadE(eB, itn);
      asm volatile("s_waitcnt vmcnt(12)\n\ts_barrier" ::: "memory");
      body(it, cur, eA);
      cur = nx;
      if (++it >= it1) break;
      nx = cur + 1; if (nx == 3) nx = 0;
      itn = (it + 1 < it1) ? it + 1 : it1 - 1;
      stageKV(itn, nx);
      loadE(eA, itn);
      asm volatile("s_waitcnt vmcnt(12)\n\ts_barrier" ::: "memory");
      body(it, cur, eB);
      cur = nx;
      if (++it >= it1) break;
    }

    // epilogue: partial sums (unnormalized)
#pragma unroll
    for (int rt = 0; rt < 2; ++rt)
#pragma unroll
      for (int j = 0; j < 4; ++j) {
        float ls = lpart[rt][j];
#pragma unroll
        for (int d = 1; d < 16; d <<= 1) ls += __shfl_xor(ls, d);
        const int row = wv * 32 + rt * 16 + q * 4 + j;
        if (po) {
#pragma unroll
          for (int dc = 0; dc < 4; ++dc)
            po[(size_t)row * 64 + dc * 16 + r] = oacc[rt][dc][j];
        } else {                                // fh: raw O into d_out
          const int ss = T * 128 + row;
#pragma unroll
          for (int dc = 0; dc < 4; ++dc)
            out[((size_t)(bb * SEQ_ + ss)) * DMODEL + hh * DHEAD + dc * 16 + r] = oacc[rt][dc][j];
        }
        if (r == 0) pl[row] = ls;
      }
  };

  // block = fh(TA) + sh(TB), 17 iters total
  int TA, a1, TB, b0, b1;
  if (role == 0) { TA = 15 - p; a1 = 16 - p; TB = p;      b0 = p + 1;  b1 = 2 * p + 2; }
  else           { TA = p;      a1 = p + 1;  TB = 15 - p; b0 = 16 - p; b1 = 32 - 2 * p; }

  run_strip(TA, 0, a1, nullptr,
            pL + ((size_t)(bh * 16 + TA)) * 256);
  run_strip(TB, b0, b1, pO1 + ((size_t)(bh * 16 + TB)) * 8192,
            pL + ((size_t)(bh * 16 + TB)) * 256 + 128);
}

// ---------------------------------------------------------------- reduce ----
// out = (out_fh + pO1_sh) / (l0 + l1) for every 128-row tile.
__global__ __launch_bounds__(256) void reduce_kernel(const float* __restrict__ pO1,
                                                     const float* __restrict__ pL,
                                                     float* __restrict__ out) {
  const int slot = blockIdx.x;                  // bh*16 + T
  const int bh = slot >> 4, T = slot & 15;
  const int bb = bh >> 4, hh = bh & 15;
  const int tid = threadIdx.x;
  const int row = tid >> 1, half = (tid & 1) * 32;

  const float l0 = pL[(size_t)slot * 256 + row];
  const float l1 = pL[(size_t)slot * 256 + 128 + row];
  const float inv = 1.0f / (l0 + l1);

  float* a = out + ((size_t)(bb * SEQ_) + T * 128 + row) * DMODEL + hh * DHEAD + half;
  const float* b = pO1 + (size_t)slot * 8192 + row * 64 + half;
#pragma unroll
  for (int k = 0; k < 8; ++k) {
    float4 x = ((const float4*)a)[k];
    float4 y = ((const float4*)b)[k];
    float4 o;
    o.x = (x.x + y.x) * inv; o.y = (x.y + y.y) * inv;
    o.z = (x.z + y.z) * inv; o.w = (x.w + y.w) * inv;
    ((float4*)a)[k] = o;
  }
}

// ------------------------------------------------------------------ launch ---
extern "C" void kernel_launch(void* const* d_in, const int* in_sizes, int n_in,
                              void* d_out, int out_size, void* d_ws, size_t ws_size,
                              hipStream_t stream) {
  const float* query = (const float*)d_in[0];
  const float* key   = (const float*)d_in[1];
  const float* value = (const float*)d_in[2];
  const float* Wq    = (const float*)d_in[3];
  const float* bq    = (const float*)d_in[4];
  const float* Wk    = (const float*)d_in[5];
  const float* bk    = (const float*)d_in[6];
  const float* Wv    = (const float*)d_in[7];
  const float* bv    = (const float*)d_in[8];
  const float* Er    = (const float*)d_in[9];

  char* ws = (char*)d_ws;
  unsigned short* qb   = (unsigned short*)(ws + (0u  << 20));  // 8MB
  unsigned short* ktil = (unsigned short*)(ws + (8u  << 20));  // 8MB
  unsigned short* vtil = (unsigned short*)(ws + (16u << 20));  // 8MB
  float*          pO1  = (float*)(ws + (24u << 20));           // 16MB [24,40)
  float*          pL   = (float*)(ws + (40u << 20));           // 512KB
  unsigned short* Wqb  = (unsigned short*)(ws + (56u << 20));  // 2MB
  unsigned short* Wkb  = (unsigned short*)(ws + (58u << 20));
  unsigned short* Wvb  = (unsigned short*)(ws + (60u << 20));
  unsigned short* Erb  = (unsigned short*)(ws + (62u << 20));  // 256KB

  conv4_kernel<<<dim3(512, 4), 256, 0, stream>>>(Wq, Wk, Wv, Er,
                                                 Wqb, Wkb, Wvb, Erb,
                                                 DMODEL * DMODEL, SEQ_ * DHEAD);

  proj3_kernel<<<dim3(32, 8, 3), 256, 0, stream>>>(query, key, value,
                                                   Wqb, Wkb, Wvb,
                                                   bq, bk, bv, qb, ktil, vtil);

  attn_kernel<<<dim3(512), 256, 0, stream>>>(qb, ktil, vtil, Erb,
                                             (float*)d_out, pO1, pL);

  reduce_kernel<<<dim3(512), 256, 0, stream>>>(pO1, pL, (float*)d_out);
}

// Round 15
// 145.053 us; speedup vs baseline: 1.6802x; 1.0188x over previous
//
#include <hip/hip_runtime.h>
#include <hip/hip_bf16.h>

typedef __attribute__((ext_vector_type(8))) short bf16x8;   // 8 bf16 = 4 VGPR (MFMA A/B frag)
typedef __attribute__((ext_vector_type(4))) float f32x4;    // MFMA C/D frag

#define DEVI __device__ __forceinline__
#define AS1 __attribute__((address_space(1)))
#define AS3 __attribute__((address_space(3)))

constexpr int SEQ_   = 2048;
constexpr int HEADS  = 16;
constexpr int DHEAD  = 64;
constexpr int DMODEL = 1024;

DEVI unsigned short f2bf(float x) {
  __hip_bfloat16 h = __float2bfloat16(x);   // RNE
  return __builtin_bit_cast(unsigned short, h);
}

DEVI f32x4 MFMA(bf16x8 a, bf16x8 b, f32x4 c) {
  return __builtin_amdgcn_mfma_f32_16x16x32_bf16(a, b, c, 0, 0, 0);
}

DEVI unsigned int cvtpk(float lo, float hi) {   // dst.lo16=bf16(lo), dst.hi16=bf16(hi)
  unsigned int u;
  asm("v_cvt_pk_bf16_f32 %0, %1, %2" : "=v"(u) : "v"(lo), "v"(hi));
  return u;
}

// ---------------------------------------------------------------- convert ---
// One launch: y=0..2 -> query/key/value (4M elems each); y=3 -> concatenated
// Wq|Wk|Wv|Er regions (3*1M + 128K elems; all region bounds are /8).
__global__ void conv_all_kernel(const float* q, const float* k, const float* v,
                                const float* Wq, const float* Wk, const float* Wv,
                                const float* Er,
                                unsigned short* Xq, unsigned short* Xk,
                                unsigned short* Xv,
                                unsigned short* Wqb, unsigned short* Wkb,
                                unsigned short* Wvb, unsigned short* Erb) {
  const int y = blockIdx.y;
  const int i = (blockIdx.x * 256 + threadIdx.x) * 8;
  const float* s;
  unsigned short* d;
  int off = i;
  if (y < 3) {
    if (i >= 2 * SEQ_ * DMODEL) return;
    s = (y == 0) ? q : (y == 1) ? k : v;
    d = (y == 0) ? Xq : (y == 1) ? Xk : Xv;
  } else {
    constexpr int NW = DMODEL * DMODEL;           // 1048576 (/8)
    if (i >= 3 * NW + SEQ_ * DHEAD) return;
    if (i < NW)          { s = Wq; d = Wqb; }
    else if (i < 2 * NW) { s = Wk; d = Wkb; off = i - NW; }
    else if (i < 3 * NW) { s = Wv; d = Wvb; off = i - 2 * NW; }
    else                 { s = Er; d = Erb; off = i - 3 * NW; }
  }
  const float4* p = (const float4*)(s + off);
  float4 v0 = p[0], v1 = p[1];
  union { unsigned short u[8]; bf16x8 v; } t;
  t.u[0] = f2bf(v0.x); t.u[1] = f2bf(v0.y); t.u[2] = f2bf(v0.z); t.u[3] = f2bf(v0.w);
  t.u[4] = f2bf(v1.x); t.u[5] = f2bf(v1.y); t.u[6] = f2bf(v1.z); t.u[7] = f2bf(v1.w);
  *(bf16x8*)(d + off) = t.v;
}

// ------------------------------------------------------------- projection ---
// z==0 (Q): out (b,h,s,d), pre-scaled by 0.125*log2(e) (exp2 softmax fold).
// z==1 (K): 4KB tiles (per 32 t) in MFMA fragment order.
// z==2 (V): 8KB tiles (per 64 t) frag order with t' = 4*(t&15) + (t>>4)
//           permutation (matches attn's b64 P-write order).
__global__ __launch_bounds__(256) void proj3_kernel(
    const unsigned short* __restrict__ X0, const unsigned short* __restrict__ X1,
    const unsigned short* __restrict__ X2,
    const unsigned short* __restrict__ W0, const unsigned short* __restrict__ W1,
    const unsigned short* __restrict__ W2,
    const float* __restrict__ bi0, const float* __restrict__ bi1,
    const float* __restrict__ bi2,
    unsigned short* __restrict__ o0, unsigned short* __restrict__ o1,
    unsigned short* __restrict__ o2) {
  const int z = blockIdx.z;
  const unsigned short* X = (z == 0) ? X0 : (z == 1) ? X1 : X2;
  const unsigned short* W = (z == 0) ? W0 : (z == 1) ? W1 : W2;
  const float* bias        = (z == 0) ? bi0 : (z == 1) ? bi1 : bi2;
  unsigned short* out      = (z == 0) ? o0 : (z == 1) ? o1 : o2;

  __shared__ unsigned short Abuf[2][128 * 32];
  __shared__ unsigned short Bbuf[2][128 * 32];
  const int tid  = threadIdx.x;
  const int lane = tid & 63, wv = tid >> 6;
  const int q = lane >> 4, r = lane & 15;
  const int wrow = wv >> 1, wcol = wv & 1;
  const int rowA0 = blockIdx.x * 128, colB0 = blockIdx.y * 128;

  const char* Ag = (const char*)(X + (size_t)rowA0 * DMODEL);
  const char* Bg = (const char*)(W + (size_t)colB0 * DMODEL);

  f32x4 acc[4][4] = {};

  auto stage = [&](int ks, int buf) {
    const int koff = ks * 64;
#pragma unroll
    for (int i = 0; i < 2; ++i) {
      const int b   = (i * 256 + tid) * 16;
      const int row = b >> 6, col = b & 63;
      __builtin_amdgcn_global_load_lds(
          (const AS1 void*)(Ag + (size_t)row * (DMODEL * 2) + koff + col),
          (AS3 void*)((char*)&Abuf[buf][0] + i * 4096 + wv * 1024),
          16, 0, 0);
      __builtin_amdgcn_global_load_lds(
          (const AS1 void*)(Bg + (size_t)row * (DMODEL * 2) + koff + col),
          (AS3 void*)((char*)&Bbuf[buf][0] + i * 4096 + wv * 1024),
          16, 0, 0);
    }
  };

  stage(0, 0);
  for (int ks = 0; ks < 32; ++ks) {
    __syncthreads();
    if (ks + 1 < 32) stage(ks + 1, (ks + 1) & 1);
    const unsigned short* A  = &Abuf[ks & 1][0];
    const unsigned short* Bt = &Bbuf[ks & 1][0];
    bf16x8 af[4], bfr[4];
#pragma unroll
    for (int t = 0; t < 4; ++t) {
      af[t]  = *(const bf16x8*)(A  + (wrow * 64 + t * 16 + r) * 32 + q * 8);
      bfr[t] = *(const bf16x8*)(Bt + (wcol * 64 + t * 16 + r) * 32 + q * 8);
    }
#pragma unroll
    for (int m = 0; m < 4; ++m)
#pragma unroll
      for (int n = 0; n < 4; ++n)
        acc[m][n] = MFMA(af[m], bfr[n], acc[m][n]);
  }

#pragma unroll
  for (int m = 0; m < 4; ++m) {
#pragma unroll
    for (int n = 0; n < 4; ++n) {
      const int e  = colB0 + wcol * 64 + n * 16 + r;
      const float bv = bias[e];
      const int h = e >> 6, dd = e & 63;
      const int nrow0 = rowA0 + wrow * 64 + m * 16 + q * 4;
      const int bb = nrow0 >> 11, ss0 = nrow0 & 2047;
      const size_t bh = (size_t)(bb * HEADS + h);
      if (z == 0) {
#pragma unroll
        for (int j = 0; j < 4; ++j)
          out[(bh * SEQ_ + (ss0 + j)) * DHEAD + dd] =
              f2bf((acc[m][n][j] + bv) * 0.1803368801111244f);   // 0.125*log2e
      } else if (z == 1) {
#pragma unroll
        for (int j = 0; j < 4; ++j) {
          const int s = ss0 + j;
          const size_t off = (bh * 64 + (size_t)(s >> 5)) * 2048
                           + (size_t)(((dd >> 5) * 2 + ((s >> 4) & 1)) * 512)
                           + (size_t)(((((dd & 31) >> 3) << 4) + (s & 15)) * 8)
                           + (dd & 7);
          out[off] = f2bf(acc[m][n][j] + bv);
        }
      } else {
        // V: 8KB tile per 64 t, t' = 4*(t&15) + (t>>4)
#pragma unroll
        for (int j = 0; j < 4; ++j) {
          const int s = ss0 + j;
          const int tile64 = s >> 6, t = s & 63;
          const int tp = 4 * (t & 15) + (t >> 4);
          const int tc = tp >> 5, u = tp & 31;
          const int ln = ((u >> 3) << 4) | (dd & 15);
          const size_t off = (bh * 32 + (size_t)tile64) * 4096
                           + (size_t)(tc * 2048 + (dd >> 4) * 512 + ln * 8 + (u & 7));
          out[off] = f2bf(acc[m][n][j] + bv);
        }
      }
    }
  }
}

// -------------------------------------------------------------- attention ---
// (R10-proven kernel; exp2f instead of __expf — log2e folded into Q.)
// 512 blocks x 256 thr (4 waves x 32 rows = 128-row tile). Each block: 17
// contiguous iters = fh(T)=[0,T+1) of one tile + sh of its complement.
// Packed-bf16 lattice gather, b64 P-write with t'-permuted V, 3-ring +
// counted s_waitcnt vmcnt(12). fh writes raw O to d_out + pL0; sh writes
// pO1 + pL1; reduce merges.
struct ErSet { bf16x8 e[8]; };

__global__ __launch_bounds__(256, 2) void attn_kernel(
    const unsigned short* __restrict__ qb, const unsigned short* __restrict__ kt,
    const unsigned short* __restrict__ vt, const unsigned short* __restrict__ Er,
    float* __restrict__ out, float* __restrict__ pO1, float* __restrict__ pL) {
  __shared__ unsigned short k_lds[3][4096];     // 8KB/buf (2x 4KB frag tiles)
  __shared__ unsigned short v_lds[3][4096];     // 8KB/buf (one 64-t permuted tile)
  __shared__ unsigned short p_lds[4][32][68];   // [s][t'] b64-written P

  const int tid  = threadIdx.x;
  const int lane = tid & 63, wv = tid >> 6;     // 4 waves
  const int q = lane >> 4, r = lane & 15;

  const int lid = blockIdx.x;
  const int xcd = lid & 7, idx = lid >> 3;
  const int bh  = (xcd << 2) | (idx & 3);       // 4 bh pinned per XCD L2
  const int jb  = idx >> 2;                     // 0..15
  const int p = jb >> 1, role = jb & 1;
  const int bb = bh >> 4, hh = bh & 15;

  const unsigned short* qbh = qb + (size_t)bh * SEQ_ * DHEAD;
  const char* ktb = (const char*)(kt + (size_t)bh * 64 * 2048);
  const char* vtb = (const char*)(vt + (size_t)bh * 32 * 4096);
  const f32x4 zero4 = {0.f, 0.f, 0.f, 0.f};

  const char* sgbase = (wv < 2) ? ktb : vtb;
  char* sdst0 = (char*)((wv < 2) ? &k_lds[0][0] : &v_lds[0][0]);
  const int shalf = (wv & 1) * 4096;
  const int soff  = lane * 16;

  auto stageKV = [&](int it, int buf) {         // 4 vmem ops, always
    const char* src = sgbase + (size_t)it * 8192 + shalf + soff;
    char* dst = sdst0 + buf * 8192 + shalf;
#pragma unroll
    for (int c = 0; c < 4; ++c)
      __builtin_amdgcn_global_load_lds((const AS1 void*)(src + c * 1024),
                                       (AS3 void*)(dst + c * 1024), 16, 0, 0);
  };

  auto run_strip = [&](int T, int it0, int it1, float* po, float* pl) {
    const int s0 = T * 128 + wv * 32;
    __syncthreads();                            // drain prev strip
    stageKV(it0, 0);

    bf16x8 qf[2][2];
#pragma unroll
    for (int rt = 0; rt < 2; ++rt) {
      qf[rt][0] = *(const bf16x8*)(qbh + (size_t)(s0 + rt * 16 + r) * DHEAD + q * 8);
      qf[rt][1] = *(const bf16x8*)(qbh + (size_t)(s0 + rt * 16 + r) * DHEAD + 32 + q * 8);
    }

    f32x4 qer[2][6];
    {                                           // lattice init: tiles 0,1
      const int lb0 = 2016 + it0 * 64 - s0;
#pragma unroll
      for (int m = 0; m < 2; ++m) {
        int l = lb0 + m * 16 + r; l = l < 2047 ? l : 2047;
        bf16x8 e0 = *(const bf16x8*)(Er + (size_t)l * DHEAD + q * 8);
        bf16x8 e1 = *(const bf16x8*)(Er + (size_t)l * DHEAD + 32 + q * 8);
#pragma unroll
        for (int rt = 0; rt < 2; ++rt)
          qer[rt][m] = MFMA(qf[rt][1], e1, MFMA(qf[rt][0], e0, zero4));
      }
    }

    auto loadE = [&](ErSet& es, int it) {       // 8 vmem ops, always
      const int lb = 2016 + it * 64 - s0;
#pragma unroll
      for (int mi = 0; mi < 4; ++mi) {
        int l = lb + 32 + mi * 16 + r;
        l = l < 2047 ? l : 2047;
        es.e[mi * 2 + 0] = *(const bf16x8*)(Er + (size_t)l * DHEAD + q * 8);
        es.e[mi * 2 + 1] = *(const bf16x8*)(Er + (size_t)l * DHEAD + 32 + q * 8);
      }
    };

    f32x4 oacc[2][4] = {};
    float lpart[2][4] = {};

    auto body = [&](int it, int cur, const ErSet& es) {
      const int t0 = it * 64;
      if (t0 > s0 + 31) return;                 // masked tail (no barriers inside)
      const unsigned short* KL = &k_lds[cur][0];
      const unsigned short* VL = &v_lds[cur][0];

      bf16x8 kf[4][2];
#pragma unroll
      for (int ct = 0; ct < 4; ++ct)
#pragma unroll
        for (int kc = 0; kc < 2; ++kc)
          kf[ct][kc] = *(const bf16x8*)(KL + (ct >> 1) * 2048 + (kc * 2 + (ct & 1)) * 512 + lane * 8);

      f32x4 s4[2][4];
      __builtin_amdgcn_s_setprio(1);
#pragma unroll
      for (int rt = 0; rt < 2; ++rt)
#pragma unroll
        for (int ct = 0; ct < 4; ++ct)
          s4[rt][ct] = MFMA(qf[rt][1], kf[ct][1], MFMA(qf[rt][0], kf[ct][0], zero4));
#pragma unroll
      for (int rt = 0; rt < 2; ++rt)
#pragma unroll
        for (int mi = 0; mi < 4; ++mi)
          qer[rt][2 + mi] = MFMA(qf[rt][1], es.e[mi * 2 + 1],
                                 MFMA(qf[rt][0], es.e[mi * 2 + 0], zero4));
      __builtin_amdgcn_s_setprio(0);

      const int d0 = t0 - s0;
#pragma unroll
      for (int rt = 0; rt < 2; ++rt) {
        const int a = 1 - rt;                   // lattice window base tile
#pragma unroll
        for (int j = 0; j < 4; ++j) {
          unsigned int pkA = cvtpk(qer[rt][a][j],     qer[rt][a + 1][j]);
          unsigned int pkB = cvtpk(qer[rt][a + 2][j], qer[rt][a + 3][j]);
          const float  s5f = qer[rt][a + 4][j];
          const int srcl = (q << 4) | ((15 + r - q * 4 - j) & 15);
          unsigned int A = (unsigned int)__shfl((int)pkA, srcl);
          unsigned int B = (unsigned int)__shfl((int)pkB, srcl);
          const float g4 = __shfl(s5f, srcl);
          const float g0 = __builtin_bit_cast(float, A << 16);
          const float g1 = __builtin_bit_cast(float, A & 0xffff0000u);
          const float g2 = __builtin_bit_cast(float, B << 16);
          const float g3 = __builtin_bit_cast(float, B & 0xffff0000u);
          const bool hi = (r > q * 4 + j);
          const float b0 = hi ? g1 : g0;
          const float b1 = hi ? g2 : g1;
          const float b2 = hi ? g3 : g2;
          const float b3 = hi ? g4 : g3;
          const int A_ = rt * 16 + q * 4 + j - r - d0;   // keep iff ct*16 <= A_
          const float p0 = (A_ >= 0)  ? exp2f(s4[rt][0][j] + b0) : 0.f;
          const float p1 = (A_ >= 16) ? exp2f(s4[rt][1][j] + b1) : 0.f;
          const float p2 = (A_ >= 32) ? exp2f(s4[rt][2][j] + b2) : 0.f;
          const float p3 = (A_ >= 48) ? exp2f(s4[rt][3][j] + b3) : 0.f;
          lpart[rt][j] += (p0 + p1) + (p2 + p3);
          const int sl = rt * 16 + q * 4 + j;
          const unsigned long long pw =
              (unsigned long long)cvtpk(p0, p1) |
              ((unsigned long long)cvtpk(p2, p3) << 32);
          *(unsigned long long*)&p_lds[wv][sl][4 * r] = pw;   // t' = 4r+ct
        }
      }

      bf16x8 vf[4][2];
#pragma unroll
      for (int dc = 0; dc < 4; ++dc)
#pragma unroll
        for (int tc = 0; tc < 2; ++tc)
          vf[dc][tc] = *(const bf16x8*)(VL + tc * 2048 + dc * 512 + lane * 8);
      __builtin_amdgcn_s_setprio(1);
#pragma unroll
      for (int rt = 0; rt < 2; ++rt) {
        bf16x8 pf0 = *(const bf16x8*)(&p_lds[wv][rt * 16 + r][0] + q * 8);
        bf16x8 pf1 = *(const bf16x8*)(&p_lds[wv][rt * 16 + r][0] + 32 + q * 8);
#pragma unroll
        for (int dc = 0; dc < 4; ++dc)
          oacc[rt][dc] = MFMA(pf1, vf[dc][1], MFMA(pf0, vf[dc][0], oacc[rt][dc]));
      }
      __builtin_amdgcn_s_setprio(0);

#pragma unroll
      for (int rt = 0; rt < 2; ++rt) { qer[rt][0] = qer[rt][4]; qer[rt][1] = qer[rt][5]; }
    };

    ErSet eA, eB;
    loadE(eA, it0);

    int it = it0, cur = 0;
    while (true) {
      int nx = cur + 1; if (nx == 3) nx = 0;
      int itn = (it + 1 < it1) ? it + 1 : it1 - 1;
      stageKV(itn, nx);
      loadE(eB, itn);
      asm volatile("s_waitcnt vmcnt(12)\n\ts_barrier" ::: "memory");
      body(it, cur, eA);
      cur = nx;
      if (++it >= it1) break;
      nx = cur + 1; if (nx == 3) nx = 0;
      itn = (it + 1 < it1) ? it + 1 : it1 - 1;
      stageKV(itn, nx);
      loadE(eA, itn);
      asm volatile("s_waitcnt vmcnt(12)\n\ts_barrier" ::: "memory");
      body(it, cur, eB);
      cur = nx;
      if (++it >= it1) break;
    }

    // epilogue: partial sums (unnormalized)
#pragma unroll
    for (int rt = 0; rt < 2; ++rt)
#pragma unroll
      for (int j = 0; j < 4; ++j) {
        float ls = lpart[rt][j];
#pragma unroll
        for (int d = 1; d < 16; d <<= 1) ls += __shfl_xor(ls, d);
        const int row = wv * 32 + rt * 16 + q * 4 + j;
        if (po) {
#pragma unroll
          for (int dc = 0; dc < 4; ++dc)
            po[(size_t)row * 64 + dc * 16 + r] = oacc[rt][dc][j];
        } else {                                // fh: raw O into d_out
          const int ss = T * 128 + row;
#pragma unroll
          for (int dc = 0; dc < 4; ++dc)
            out[((size_t)(bb * SEQ_ + ss)) * DMODEL + hh * DHEAD + dc * 16 + r] = oacc[rt][dc][j];
        }
        if (r == 0) pl[row] = ls;
      }
  };

  // block = fh(TA) + sh(TB), 17 iters total
  int TA, a1, TB, b0, b1;
  if (role == 0) { TA = 15 - p; a1 = 16 - p; TB = p;      b0 = p + 1;  b1 = 2 * p + 2; }
  else           { TA = p;      a1 = p + 1;  TB = 15 - p; b0 = 16 - p; b1 = 32 - 2 * p; }

  run_strip(TA, 0, a1, nullptr,
            pL + ((size_t)(bh * 16 + TA)) * 256);
  run_strip(TB, b0, b1, pO1 + ((size_t)(bh * 16 + TB)) * 8192,
            pL + ((size_t)(bh * 16 + TB)) * 256 + 128);
}

// ---------------------------------------------------------------- reduce ----
// out = (out_fh + pO1_sh) / (l0 + l1) for every 128-row tile.
__global__ __launch_bounds__(256) void reduce_kernel(const float* __restrict__ pO1,
                                                     const float* __restrict__ pL,
                                                     float* __restrict__ out) {
  const int slot = blockIdx.x;                  // bh*16 + T
  const int bh = slot >> 4, T = slot & 15;
  const int bb = bh >> 4, hh = bh & 15;
  const int tid = threadIdx.x;
  const int row = tid >> 1, half = (tid & 1) * 32;

  const float l0 = pL[(size_t)slot * 256 + row];
  const float l1 = pL[(size_t)slot * 256 + 128 + row];
  const float inv = 1.0f / (l0 + l1);

  float* a = out + ((size_t)(bb * SEQ_) + T * 128 + row) * DMODEL + hh * DHEAD + half;
  const float* b = pO1 + (size_t)slot * 8192 + row * 64 + half;
#pragma unroll
  for (int k = 0; k < 8; ++k) {
    float4 x = ((const float4*)a)[k];
    float4 y = ((const float4*)b)[k];
    float4 o;
    o.x = (x.x + y.x) * inv; o.y = (x.y + y.y) * inv;
    o.z = (x.z + y.z) * inv; o.w = (x.w + y.w) * inv;
    ((float4*)a)[k] = o;
  }
}

// ------------------------------------------------------------------ launch ---
extern "C" void kernel_launch(void* const* d_in, const int* in_sizes, int n_in,
                              void* d_out, int out_size, void* d_ws, size_t ws_size,
                              hipStream_t stream) {
  const float* query = (const float*)d_in[0];
  const float* key   = (const float*)d_in[1];
  const float* value = (const float*)d_in[2];
  const float* Wq    = (const float*)d_in[3];
  const float* bq    = (const float*)d_in[4];
  const float* Wk    = (const float*)d_in[5];
  const float* bk    = (const float*)d_in[6];
  const float* Wv    = (const float*)d_in[7];
  const float* bv    = (const float*)d_in[8];
  const float* Er    = (const float*)d_in[9];

  char* ws = (char*)d_ws;
  unsigned short* qb   = (unsigned short*)(ws + (0u  << 20));  // 8MB
  unsigned short* ktil = (unsigned short*)(ws + (8u  << 20));  // 8MB
  unsigned short* vtil = (unsigned short*)(ws + (16u << 20));  // 8MB
  float*          pO1  = (float*)(ws + (24u << 20));           // 16MB [24,40) (Xq dead post-proj)
  float*          pL   = (float*)(ws + (40u << 20));           // 512KB (Xk dead post-proj)
  unsigned short* Xq   = (unsigned short*)(ws + (32u << 20));  // proj inputs (pre-attn only)
  unsigned short* Xk   = (unsigned short*)(ws + (40u << 20));
  unsigned short* Xv   = (unsigned short*)(ws + (48u << 20));
  unsigned short* Wqb  = (unsigned short*)(ws + (56u << 20));  // 2MB
  unsigned short* Wkb  = (unsigned short*)(ws + (58u << 20));
  unsigned short* Wvb  = (unsigned short*)(ws + (60u << 20));
  unsigned short* Erb  = (unsigned short*)(ws + (62u << 20));  // 256KB

  conv_all_kernel<<<dim3(2048, 4), 256, 0, stream>>>(query, key, value,
                                                     Wq, Wk, Wv, Er,
                                                     Xq, Xk, Xv,
                                                     Wqb, Wkb, Wvb, Erb);

  proj3_kernel<<<dim3(32, 8, 3), 256, 0, stream>>>(Xq, Xk, Xv, Wqb, Wkb, Wvb,
                                                   bq, bk, bv, qb, ktil, vtil);

  attn_kernel<<<dim3(512), 256, 0, stream>>>(qb, ktil, vtil, Erb,
                                             (float*)d_out, pO1, pL);

  reduce_kernel<<<dim3(512), 256, 0, stream>>>(pO1, pL, (float*)d_out);
}

// Round 16
// 140.316 us; speedup vs baseline: 1.7369x; 1.0338x over previous
//
#include <hip/hip_runtime.h>
#include <hip/hip_bf16.h>

typedef __attribute__((ext_vector_type(8))) short bf16x8;   // 8 bf16 = 4 VGPR (MFMA A/B frag)
typedef __attribute__((ext_vector_type(4))) float f32x4;    // MFMA C/D frag

#define DEVI __device__ __forceinline__
#define AS1 __attribute__((address_space(1)))
#define AS3 __attribute__((address_space(3)))

constexpr int SEQ_   = 2048;
constexpr int HEADS  = 16;
constexpr int DHEAD  = 64;
constexpr int DMODEL = 1024;

DEVI unsigned short f2bf(float x) {
  __hip_bfloat16 h = __float2bfloat16(x);   // RNE
  return __builtin_bit_cast(unsigned short, h);
}

DEVI f32x4 MFMA(bf16x8 a, bf16x8 b, f32x4 c) {
  return __builtin_amdgcn_mfma_f32_16x16x32_bf16(a, b, c, 0, 0, 0);
}

DEVI unsigned int cvtpk(float lo, float hi) {   // dst.lo16=bf16(lo), dst.hi16=bf16(hi)
  unsigned int u;
  asm("v_cvt_pk_bf16_f32 %0, %1, %2" : "=v"(u) : "v"(lo), "v"(hi));
  return u;
}

DEVI float exp2v(float x) {                     // raw v_exp_f32: D = 2^S0 (1 VALU op)
  float y;
  asm("v_exp_f32 %0, %1" : "=v"(y) : "v"(x));
  return y;
}

// ---------------------------------------------------------------- convert ---
// One launch: y=0..2 -> query/key/value (4M elems each); y=3 -> concatenated
// Wq|Wk|Wv|Er regions (3*1M + 128K elems; all region bounds are /8).
__global__ void conv_all_kernel(const float* q, const float* k, const float* v,
                                const float* Wq, const float* Wk, const float* Wv,
                                const float* Er,
                                unsigned short* Xq, unsigned short* Xk,
                                unsigned short* Xv,
                                unsigned short* Wqb, unsigned short* Wkb,
                                unsigned short* Wvb, unsigned short* Erb) {
  const int y = blockIdx.y;
  const int i = (blockIdx.x * 256 + threadIdx.x) * 8;
  const float* s;
  unsigned short* d;
  int off = i;
  if (y < 3) {
    if (i >= 2 * SEQ_ * DMODEL) return;
    s = (y == 0) ? q : (y == 1) ? k : v;
    d = (y == 0) ? Xq : (y == 1) ? Xk : Xv;
  } else {
    constexpr int NW = DMODEL * DMODEL;           // 1048576 (/8)
    if (i >= 3 * NW + SEQ_ * DHEAD) return;
    if (i < NW)          { s = Wq; d = Wqb; }
    else if (i < 2 * NW) { s = Wk; d = Wkb; off = i - NW; }
    else if (i < 3 * NW) { s = Wv; d = Wvb; off = i - 2 * NW; }
    else                 { s = Er; d = Erb; off = i - 3 * NW; }
  }
  const float4* p = (const float4*)(s + off);
  float4 v0 = p[0], v1 = p[1];
  union { unsigned short u[8]; bf16x8 v; } t;
  t.u[0] = f2bf(v0.x); t.u[1] = f2bf(v0.y); t.u[2] = f2bf(v0.z); t.u[3] = f2bf(v0.w);
  t.u[4] = f2bf(v1.x); t.u[5] = f2bf(v1.y); t.u[6] = f2bf(v1.z); t.u[7] = f2bf(v1.w);
  *(bf16x8*)(d + off) = t.v;
}

// ------------------------------------------------------------- projection ---
// z==0 (Q): out (b,h,s,d), pre-scaled by 0.125*log2(e) (exp2 softmax fold).
// z==1 (K): 4KB tiles (per 32 t) in MFMA fragment order.
// z==2 (V): 8KB tiles (per 64 t) frag order with t' = 4*(t&15) + (t>>4)
//           permutation (matches attn's b64 P-write order).
__global__ __launch_bounds__(256) void proj3_kernel(
    const unsigned short* __restrict__ X0, const unsigned short* __restrict__ X1,
    const unsigned short* __restrict__ X2,
    const unsigned short* __restrict__ W0, const unsigned short* __restrict__ W1,
    const unsigned short* __restrict__ W2,
    const float* __restrict__ bi0, const float* __restrict__ bi1,
    const float* __restrict__ bi2,
    unsigned short* __restrict__ o0, unsigned short* __restrict__ o1,
    unsigned short* __restrict__ o2) {
  const int z = blockIdx.z;
  const unsigned short* X = (z == 0) ? X0 : (z == 1) ? X1 : X2;
  const unsigned short* W = (z == 0) ? W0 : (z == 1) ? W1 : W2;
  const float* bias        = (z == 0) ? bi0 : (z == 1) ? bi1 : bi2;
  unsigned short* out      = (z == 0) ? o0 : (z == 1) ? o1 : o2;

  __shared__ unsigned short Abuf[2][128 * 32];
  __shared__ unsigned short Bbuf[2][128 * 32];
  const int tid  = threadIdx.x;
  const int lane = tid & 63, wv = tid >> 6;
  const int q = lane >> 4, r = lane & 15;
  const int wrow = wv >> 1, wcol = wv & 1;
  const int rowA0 = blockIdx.x * 128, colB0 = blockIdx.y * 128;

  const char* Ag = (const char*)(X + (size_t)rowA0 * DMODEL);
  const char* Bg = (const char*)(W + (size_t)colB0 * DMODEL);

  f32x4 acc[4][4] = {};

  auto stage = [&](int ks, int buf) {
    const int koff = ks * 64;
#pragma unroll
    for (int i = 0; i < 2; ++i) {
      const int b   = (i * 256 + tid) * 16;
      const int row = b >> 6, col = b & 63;
      __builtin_amdgcn_global_load_lds(
          (const AS1 void*)(Ag + (size_t)row * (DMODEL * 2) + koff + col),
          (AS3 void*)((char*)&Abuf[buf][0] + i * 4096 + wv * 1024),
          16, 0, 0);
      __builtin_amdgcn_global_load_lds(
          (const AS1 void*)(Bg + (size_t)row * (DMODEL * 2) + koff + col),
          (AS3 void*)((char*)&Bbuf[buf][0] + i * 4096 + wv * 1024),
          16, 0, 0);
    }
  };

  stage(0, 0);
  for (int ks = 0; ks < 32; ++ks) {
    __syncthreads();
    if (ks + 1 < 32) stage(ks + 1, (ks + 1) & 1);
    const unsigned short* A  = &Abuf[ks & 1][0];
    const unsigned short* Bt = &Bbuf[ks & 1][0];
    bf16x8 af[4], bfr[4];
#pragma unroll
    for (int t = 0; t < 4; ++t) {
      af[t]  = *(const bf16x8*)(A  + (wrow * 64 + t * 16 + r) * 32 + q * 8);
      bfr[t] = *(const bf16x8*)(Bt + (wcol * 64 + t * 16 + r) * 32 + q * 8);
    }
#pragma unroll
    for (int m = 0; m < 4; ++m)
#pragma unroll
      for (int n = 0; n < 4; ++n)
        acc[m][n] = MFMA(af[m], bfr[n], acc[m][n]);
  }

#pragma unroll
  for (int m = 0; m < 4; ++m) {
#pragma unroll
    for (int n = 0; n < 4; ++n) {
      const int e  = colB0 + wcol * 64 + n * 16 + r;
      const float bv = bias[e];
      const int h = e >> 6, dd = e & 63;
      const int nrow0 = rowA0 + wrow * 64 + m * 16 + q * 4;
      const int bb = nrow0 >> 11, ss0 = nrow0 & 2047;
      const size_t bh = (size_t)(bb * HEADS + h);
      if (z == 0) {
#pragma unroll
        for (int j = 0; j < 4; ++j)
          out[(bh * SEQ_ + (ss0 + j)) * DHEAD + dd] =
              f2bf((acc[m][n][j] + bv) * 0.1803368801111244f);   // 0.125*log2e
      } else if (z == 1) {
#pragma unroll
        for (int j = 0; j < 4; ++j) {
          const int s = ss0 + j;
          const size_t off = (bh * 64 + (size_t)(s >> 5)) * 2048
                           + (size_t)(((dd >> 5) * 2 + ((s >> 4) & 1)) * 512)
                           + (size_t)(((((dd & 31) >> 3) << 4) + (s & 15)) * 8)
                           + (dd & 7);
          out[off] = f2bf(acc[m][n][j] + bv);
        }
      } else {
        // V: 8KB tile per 64 t, t' = 4*(t&15) + (t>>4)
#pragma unroll
        for (int j = 0; j < 4; ++j) {
          const int s = ss0 + j;
          const int tile64 = s >> 6, t = s & 63;
          const int tp = 4 * (t & 15) + (t >> 4);
          const int tc = tp >> 5, u = tp & 31;
          const int ln = ((u >> 3) << 4) | (dd & 15);
          const size_t off = (bh * 32 + (size_t)tile64) * 4096
                           + (size_t)(tc * 2048 + (dd >> 4) * 512 + ln * 8 + (u & 7));
          out[off] = f2bf(acc[m][n][j] + bv);
        }
      }
    }
  }
}

// -------------------------------------------------------------- attention ---
// (R10-proven structure; exp via raw v_exp_f32 — log2e folded into Q.)
// 512 blocks x 256 thr (4 waves x 32 rows = 128-row tile). Each block: 17
// contiguous iters = fh(T)=[0,T+1) of one tile + sh of its complement.
// Packed-bf16 lattice gather, b64 P-write with t'-permuted V, 3-ring +
// counted s_waitcnt vmcnt(12). fh writes raw O to d_out + pL0; sh writes
// pO1 + pL1; reduce merges.
struct ErSet { bf16x8 e[8]; };

__global__ __launch_bounds__(256, 2) void attn_kernel(
    const unsigned short* __restrict__ qb, const unsigned short* __restrict__ kt,
    const unsigned short* __restrict__ vt, const unsigned short* __restrict__ Er,
    float* __restrict__ out, float* __restrict__ pO1, float* __restrict__ pL) {
  __shared__ unsigned short k_lds[3][4096];     // 8KB/buf (2x 4KB frag tiles)
  __shared__ unsigned short v_lds[3][4096];     // 8KB/buf (one 64-t permuted tile)
  __shared__ unsigned short p_lds[4][32][68];   // [s][t'] b64-written P

  const int tid  = threadIdx.x;
  const int lane = tid & 63, wv = tid >> 6;     // 4 waves
  const int q = lane >> 4, r = lane & 15;

  const int lid = blockIdx.x;
  const int xcd = lid & 7, idx = lid >> 3;
  const int bh  = (xcd << 2) | (idx & 3);       // 4 bh pinned per XCD L2
  const int jb  = idx >> 2;                     // 0..15
  const int p = jb >> 1, role = jb & 1;
  const int bb = bh >> 4, hh = bh & 15;

  const unsigned short* qbh = qb + (size_t)bh * SEQ_ * DHEAD;
  const char* ktb = (const char*)(kt + (size_t)bh * 64 * 2048);
  const char* vtb = (const char*)(vt + (size_t)bh * 32 * 4096);
  const f32x4 zero4 = {0.f, 0.f, 0.f, 0.f};

  const char* sgbase = (wv < 2) ? ktb : vtb;
  char* sdst0 = (char*)((wv < 2) ? &k_lds[0][0] : &v_lds[0][0]);
  const int shalf = (wv & 1) * 4096;
  const int soff  = lane * 16;

  auto stageKV = [&](int it, int buf) {         // 4 vmem ops, always
    const char* src = sgbase + (size_t)it * 8192 + shalf + soff;
    char* dst = sdst0 + buf * 8192 + shalf;
#pragma unroll
    for (int c = 0; c < 4; ++c)
      __builtin_amdgcn_global_load_lds((const AS1 void*)(src + c * 1024),
                                       (AS3 void*)(dst + c * 1024), 16, 0, 0);
  };

  auto run_strip = [&](int T, int it0, int it1, float* po, float* pl) {
    const int s0 = T * 128 + wv * 32;
    __syncthreads();                            // drain prev strip
    stageKV(it0, 0);

    bf16x8 qf[2][2];
#pragma unroll
    for (int rt = 0; rt < 2; ++rt) {
      qf[rt][0] = *(const bf16x8*)(qbh + (size_t)(s0 + rt * 16 + r) * DHEAD + q * 8);
      qf[rt][1] = *(const bf16x8*)(qbh + (size_t)(s0 + rt * 16 + r) * DHEAD + 32 + q * 8);
    }

    f32x4 qer[2][6];
    {                                           // lattice init: tiles 0,1
      const int lb0 = 2016 + it0 * 64 - s0;
#pragma unroll
      for (int m = 0; m < 2; ++m) {
        int l = lb0 + m * 16 + r; l = l < 2047 ? l : 2047;
        bf16x8 e0 = *(const bf16x8*)(Er + (size_t)l * DHEAD + q * 8);
        bf16x8 e1 = *(const bf16x8*)(Er + (size_t)l * DHEAD + 32 + q * 8);
#pragma unroll
        for (int rt = 0; rt < 2; ++rt)
          qer[rt][m] = MFMA(qf[rt][1], e1, MFMA(qf[rt][0], e0, zero4));
      }
    }

    auto loadE = [&](ErSet& es, int it) {       // 8 vmem ops, always
      const int lb = 2016 + it * 64 - s0;
#pragma unroll
      for (int mi = 0; mi < 4; ++mi) {
        int l = lb + 32 + mi * 16 + r;
        l = l < 2047 ? l : 2047;
        es.e[mi * 2 + 0] = *(const bf16x8*)(Er + (size_t)l * DHEAD + q * 8);
        es.e[mi * 2 + 1] = *(const bf16x8*)(Er + (size_t)l * DHEAD + 32 + q * 8);
      }
    };

    f32x4 oacc[2][4] = {};
    float lpart[2][4] = {};

    auto body = [&](int it, int cur, const ErSet& es) {
      const int t0 = it * 64;
      if (t0 > s0 + 31) return;                 // masked tail (no barriers inside)
      const unsigned short* KL = &k_lds[cur][0];
      const unsigned short* VL = &v_lds[cur][0];

      bf16x8 kf[4][2];
#pragma unroll
      for (int ct = 0; ct < 4; ++ct)
#pragma unroll
        for (int kc = 0; kc < 2; ++kc)
          kf[ct][kc] = *(const bf16x8*)(KL + (ct >> 1) * 2048 + (kc * 2 + (ct & 1)) * 512 + lane * 8);

      f32x4 s4[2][4];
      __builtin_amdgcn_s_setprio(1);
#pragma unroll
      for (int rt = 0; rt < 2; ++rt)
#pragma unroll
        for (int ct = 0; ct < 4; ++ct)
          s4[rt][ct] = MFMA(qf[rt][1], kf[ct][1], MFMA(qf[rt][0], kf[ct][0], zero4));
#pragma unroll
      for (int rt = 0; rt < 2; ++rt)
#pragma unroll
        for (int mi = 0; mi < 4; ++mi)
          qer[rt][2 + mi] = MFMA(qf[rt][1], es.e[mi * 2 + 1],
                                 MFMA(qf[rt][0], es.e[mi * 2 + 0], zero4));
      __builtin_amdgcn_s_setprio(0);

      const int d0 = t0 - s0;
#pragma unroll
      for (int rt = 0; rt < 2; ++rt) {
        const int a = 1 - rt;                   // lattice window base tile
#pragma unroll
        for (int j = 0; j < 4; ++j) {
          unsigned int pkA = cvtpk(qer[rt][a][j],     qer[rt][a + 1][j]);
          unsigned int pkB = cvtpk(qer[rt][a + 2][j], qer[rt][a + 3][j]);
          const float  s5f = qer[rt][a + 4][j];
          const int srcl = (q << 4) | ((15 + r - q * 4 - j) & 15);
          unsigned int A = (unsigned int)__shfl((int)pkA, srcl);
          unsigned int B = (unsigned int)__shfl((int)pkB, srcl);
          const float g4 = __shfl(s5f, srcl);
          const float g0 = __builtin_bit_cast(float, A << 16);
          const float g1 = __builtin_bit_cast(float, A & 0xffff0000u);
          const float g2 = __builtin_bit_cast(float, B << 16);
          const float g3 = __builtin_bit_cast(float, B & 0xffff0000u);
          const bool hi = (r > q * 4 + j);
          const float b0 = hi ? g1 : g0;
          const float b1 = hi ? g2 : g1;
          const float b2 = hi ? g3 : g2;
          const float b3 = hi ? g4 : g3;
          const int A_ = rt * 16 + q * 4 + j - r - d0;   // keep iff ct*16 <= A_
          const float p0 = (A_ >= 0)  ? exp2v(s4[rt][0][j] + b0) : 0.f;
          const float p1 = (A_ >= 16) ? exp2v(s4[rt][1][j] + b1) : 0.f;
          const float p2 = (A_ >= 32) ? exp2v(s4[rt][2][j] + b2) : 0.f;
          const float p3 = (A_ >= 48) ? exp2v(s4[rt][3][j] + b3) : 0.f;
          lpart[rt][j] += (p0 + p1) + (p2 + p3);
          const int sl = rt * 16 + q * 4 + j;
          const unsigned long long pw =
              (unsigned long long)cvtpk(p0, p1) |
              ((unsigned long long)cvtpk(p2, p3) << 32);
          *(unsigned long long*)&p_lds[wv][sl][4 * r] = pw;   // t' = 4r+ct
        }
      }

      bf16x8 vf[4][2];
#pragma unroll
      for (int dc = 0; dc < 4; ++dc)
#pragma unroll
        for (int tc = 0; tc < 2; ++tc)
          vf[dc][tc] = *(const bf16x8*)(VL + tc * 2048 + dc * 512 + lane * 8);
      __builtin_amdgcn_s_setprio(1);
#pragma unroll
      for (int rt = 0; rt < 2; ++rt) {
        bf16x8 pf0 = *(const bf16x8*)(&p_lds[wv][rt * 16 + r][0] + q * 8);
        bf16x8 pf1 = *(const bf16x8*)(&p_lds[wv][rt * 16 + r][0] + 32 + q * 8);
#pragma unroll
        for (int dc = 0; dc < 4; ++dc)
          oacc[rt][dc] = MFMA(pf1, vf[dc][1], MFMA(pf0, vf[dc][0], oacc[rt][dc]));
      }
      __builtin_amdgcn_s_setprio(0);

#pragma unroll
      for (int rt = 0; rt < 2; ++rt) { qer[rt][0] = qer[rt][4]; qer[rt][1] = qer[rt][5]; }
    };

    ErSet eA, eB;
    loadE(eA, it0);

    int it = it0, cur = 0;
    while (true) {
      int nx = cur + 1; if (nx == 3) nx = 0;
      int itn = (it + 1 < it1) ? it + 1 : it1 - 1;
      stageKV(itn, nx);
      loadE(eB, itn);
      asm volatile("s_waitcnt vmcnt(12)\n\ts_barrier" ::: "memory");
      body(it, cur, eA);
      cur = nx;
      if (++it >= it1) break;
      nx = cur + 1; if (nx == 3) nx = 0;
      itn = (it + 1 < it1) ? it + 1 : it1 - 1;
      stageKV(itn, nx);
      loadE(eA, itn);
      asm volatile("s_waitcnt vmcnt(12)\n\ts_barrier" ::: "memory");
      body(it, cur, eB);
      cur = nx;
      if (++it >= it1) break;
    }

    // epilogue: partial sums (unnormalized)
#pragma unroll
    for (int rt = 0; rt < 2; ++rt)
#pragma unroll
      for (int j = 0; j < 4; ++j) {
        float ls = lpart[rt][j];
#pragma unroll
        for (int d = 1; d < 16; d <<= 1) ls += __shfl_xor(ls, d);
        const int row = wv * 32 + rt * 16 + q * 4 + j;
        if (po) {
#pragma unroll
          for (int dc = 0; dc < 4; ++dc)
            po[(size_t)row * 64 + dc * 16 + r] = oacc[rt][dc][j];
        } else {                                // fh: raw O into d_out
          const int ss = T * 128 + row;
#pragma unroll
          for (int dc = 0; dc < 4; ++dc)
            out[((size_t)(bb * SEQ_ + ss)) * DMODEL + hh * DHEAD + dc * 16 + r] = oacc[rt][dc][j];
        }
        if (r == 0) pl[row] = ls;
      }
  };

  // block = fh(TA) + sh(TB), 17 iters total
  int TA, a1, TB, b0, b1;
  if (role == 0) { TA = 15 - p; a1 = 16 - p; TB = p;      b0 = p + 1;  b1 = 2 * p + 2; }
  else           { TA = p;      a1 = p + 1;  TB = 15 - p; b0 = 16 - p; b1 = 32 - 2 * p; }

  run_strip(TA, 0, a1, nullptr,
            pL + ((size_t)(bh * 16 + TA)) * 256);
  run_strip(TB, b0, b1, pO1 + ((size_t)(bh * 16 + TB)) * 8192,
            pL + ((size_t)(bh * 16 + TB)) * 256 + 128);
}

// ---------------------------------------------------------------- reduce ----
// out = (out_fh + pO1_sh) / (l0 + l1) for every 128-row tile.
__global__ __launch_bounds__(256) void reduce_kernel(const float* __restrict__ pO1,
                                                     const float* __restrict__ pL,
                                                     float* __restrict__ out) {
  const int slot = blockIdx.x;                  // bh*16 + T
  const int bh = slot >> 4, T = slot & 15;
  const int bb = bh >> 4, hh = bh & 15;
  const int tid = threadIdx.x;
  const int row = tid >> 1, half = (tid & 1) * 32;

  const float l0 = pL[(size_t)slot * 256 + row];
  const float l1 = pL[(size_t)slot * 256 + 128 + row];
  const float inv = 1.0f / (l0 + l1);

  float* a = out + ((size_t)(bb * SEQ_) + T * 128 + row) * DMODEL + hh * DHEAD + half;
  const float* b = pO1 + (size_t)slot * 8192 + row * 64 + half;
#pragma unroll
  for (int k = 0; k < 8; ++k) {
    float4 x = ((const float4*)a)[k];
    float4 y = ((const float4*)b)[k];
    float4 o;
    o.x = (x.x + y.x) * inv; o.y = (x.y + y.y) * inv;
    o.z = (x.z + y.z) * inv; o.w = (x.w + y.w) * inv;
    ((float4*)a)[k] = o;
  }
}

// ------------------------------------------------------------------ launch ---
extern "C" void kernel_launch(void* const* d_in, const int* in_sizes, int n_in,
                              void* d_out, int out_size, void* d_ws, size_t ws_size,
                              hipStream_t stream) {
  const float* query = (const float*)d_in[0];
  const float* key   = (const float*)d_in[1];
  const float* value = (const float*)d_in[2];
  const float* Wq    = (const float*)d_in[3];
  const float* bq    = (const float*)d_in[4];
  const float* Wk    = (const float*)d_in[5];
  const float* bk    = (const float*)d_in[6];
  const float* Wv    = (const float*)d_in[7];
  const float* bv    = (const float*)d_in[8];
  const float* Er    = (const float*)d_in[9];

  char* ws = (char*)d_ws;
  unsigned short* qb   = (unsigned short*)(ws + (0u  << 20));  // 8MB
  unsigned short* ktil = (unsigned short*)(ws + (8u  << 20));  // 8MB
  unsigned short* vtil = (unsigned short*)(ws + (16u << 20));  // 8MB
  float*          pO1  = (float*)(ws + (24u << 20));           // 16MB [24,40) (Xq dead post-proj)
  float*          pL   = (float*)(ws + (40u << 20));           // 512KB (Xk dead post-proj)
  unsigned short* Xq   = (unsigned short*)(ws + (32u << 20));  // proj inputs (pre-attn only)
  unsigned short* Xk   = (unsigned short*)(ws + (40u << 20));
  unsigned short* Xv   = (unsigned short*)(ws + (48u << 20));
  unsigned short* Wqb  = (unsigned short*)(ws + (56u << 20));  // 2MB
  unsigned short* Wkb  = (unsigned short*)(ws + (58u << 20));
  unsigned short* Wvb  = (unsigned short*)(ws + (60u << 20));
  unsigned short* Erb  = (unsigned short*)(ws + (62u << 20));  // 256KB

  conv_all_kernel<<<dim3(2048, 4), 256, 0, stream>>>(query, key, value,
                                                     Wq, Wk, Wv, Er,
                                                     Xq, Xk, Xv,
                                                     Wqb, Wkb, Wvb, Erb);

  proj3_kernel<<<dim3(32, 8, 3), 256, 0, stream>>>(Xq, Xk, Xv, Wqb, Wkb, Wvb,
                                                   bq, bk, bv, qb, ktil, vtil);

  attn_kernel<<<dim3(512), 256, 0, stream>>>(qb, ktil, vtil, Erb,
                                             (float*)d_out, pO1, pL);

  reduce_kernel<<<dim3(512), 256, 0, stream>>>(pO1, pL, (float*)d_out);
}